// Round 1
// baseline (695.238 us; speedup 1.0000x reference)
//
#include <hip/hip_runtime.h>
#include <cstdint>

typedef unsigned short u16;
typedef short short8 __attribute__((ext_vector_type(8)));
typedef float floatx4 __attribute__((ext_vector_type(4)));

#define B_ 4
#define L_ 2048
#define D_ 512
#define P_ 128
#define V_ 8
#define BL (B_ * L_)        // 8192
#define PI_F 3.14159265358979323846f

__device__ inline u16 f2b(float f) {
    unsigned u = __float_as_uint(f);
    unsigned r = u + 0x7FFFu + ((u >> 16) & 1u);
    return (u16)(r >> 16);
}
__device__ inline float b2f(u16 h) {
    return __uint_as_float(((unsigned)h) << 16);
}
__device__ inline float gelu_f(float v) {
    return 0.5f * v * (1.0f + erff(v * 0.70710678118654752f));
}
__device__ inline float sigm(float v) {
    return 1.0f / (1.0f + expf(-v));
}

// ---------------------------------------------------------------------------
// Tiled bf16 MFMA GEMM:  C[m,n] = epi( sum_k A[m,k]*W[n,k] + bias[n] )
// A: (M x K) bf16 row-major (lda elems), W: (Npad x K) bf16 row-major,
// M multiple of 128, K multiple of 32, W rows padded to multiple of 128.
// ---------------------------------------------------------------------------
enum { EPI_F32 = 0, EPI_BF16 = 1, EPI_GELU_BF16 = 2, EPI_RESID_F32 = 3 };

template <int EPI>
__global__ __launch_bounds__(256)
void gemm_bt(const u16* __restrict__ A, int lda,
             const u16* __restrict__ W,
             const float* __restrict__ bias,
             void* __restrict__ Cout, int ldc,
             int N, int K,
             const float* __restrict__ resid)
{
    __shared__ u16 As[128][40];   // 32 k + pad 8 -> 80B row stride (16B aligned)
    __shared__ u16 Bs[128][40];
    const int tid  = threadIdx.x;
    const int mt   = blockIdx.x, nt = blockIdx.y;
    const int lane = tid & 63;
    const int wid  = tid >> 6;
    const int wm   = wid & 1, wn = wid >> 1;
    const int l16  = lane & 15, quad = lane >> 4;

    floatx4 acc[4][4] = {};

    const u16* Ab = A + (size_t)(mt * 128) * lda;
    const u16* Wb = W + (size_t)(nt * 128) * K;

    for (int k0 = 0; k0 < K; k0 += 32) {
        __syncthreads();
#pragma unroll
        for (int i = 0; i < 2; i++) {
            int idx = tid + i * 256;
            int row = idx >> 2;
            int kc  = (idx & 3) << 3;
            uint4 av = *(const uint4*)(Ab + (size_t)row * lda + k0 + kc);
            *(uint4*)(&As[row][kc]) = av;
            uint4 bv = *(const uint4*)(Wb + (size_t)row * K + k0 + kc);
            *(uint4*)(&Bs[row][kc]) = bv;
        }
        __syncthreads();
        short8 a[4], b[4];
#pragma unroll
        for (int i = 0; i < 4; i++)
            a[i] = *(const short8*)(&As[wm * 64 + i * 16 + l16][quad * 8]);
#pragma unroll
        for (int j = 0; j < 4; j++)
            b[j] = *(const short8*)(&Bs[wn * 64 + j * 16 + l16][quad * 8]);
#pragma unroll
        for (int i = 0; i < 4; i++)
#pragma unroll
            for (int j = 0; j < 4; j++)
                acc[i][j] = __builtin_amdgcn_mfma_f32_16x16x32_bf16(a[i], b[j], acc[i][j], 0, 0, 0);
    }

#pragma unroll
    for (int i = 0; i < 4; i++) {
#pragma unroll
        for (int j = 0; j < 4; j++) {
#pragma unroll
            for (int r = 0; r < 4; r++) {
                int grow = mt * 128 + wm * 64 + i * 16 + quad * 4 + r;
                int gcol = nt * 128 + wn * 64 + j * 16 + l16;
                if (gcol < N) {
                    float v = acc[i][j][r] + bias[gcol];
                    size_t off = (size_t)grow * ldc + gcol;
                    if (EPI == EPI_F32)            ((float*)Cout)[off] = v;
                    else if (EPI == EPI_BF16)      ((u16*)Cout)[off] = f2b(v);
                    else if (EPI == EPI_GELU_BF16) ((u16*)Cout)[off] = f2b(gelu_f(v));
                    else                           ((float*)Cout)[off] = v + resid[off];
                }
            }
        }
    }
}

// ---------------------------------------------------------------------------
// Weight prep: cast fp32 weights -> bf16, build concatenations + pads.
// ---------------------------------------------------------------------------
__global__ __launch_bounds__(256)
void prep_weights(const float* tw, const float* pi0, const float* m1v, const float* mag, const float* qo,
                  const float* ke, const float* ve, const float* sg,
                  const float* pi2, const float* cp, const float* sk0, const float* sk2,
                  const float* m1o, const float* o1, const float* o2,
                  const float* tw_b, const float* pi0_b, const float* m1v_b, const float* mag_b, const float* qo_b,
                  const float* ke_b, const float* ve_b, const float* sg_b,
                  u16* wcat1, float* bcat1, u16* kesgw, float* kesgb,
                  u16* pi2w, u16* cpw, u16* sk0w, u16* sk2w, u16* m1ow, u16* o1w, u16* o2w)
{
    int idx = blockIdx.x * 256 + threadIdx.x;
    const int n0 = 2560 * 512;
    const int n1 = n0 + 256 * 512;
    const int n2 = n1 + 512 * 512;
    const int n3 = n2 + 512 * 512;
    const int n4 = n3 + 512 * 1024;
    const int n5 = n4 + 128 * 512;
    const int n6 = n5 + 512 * 512;
    const int n7 = n6 + 1024 * 2560;
    const int n8 = n7 + 512 * 1024;
    const int n9 = n8 + 2560;
    const int n10 = n9 + 256;
    if (idx < n0) {
        int r = idx >> 9, k = idx & 511;
        const float* s = (r < 512) ? tw : (r < 1024) ? pi0 : (r < 1536) ? m1v : (r < 2048) ? mag : qo;
        wcat1[idx] = f2b(s[(r & 511) * 512 + k]);
    } else if (idx < n1) {
        int i = idx - n0; int r = i >> 9, k = i & 511;
        float v;
        if (r < 128)      v = ke[r * 512 + k];
        else if (r < 136) v = ve[(r - 128) * 512 + k];
        else if (r == 136) v = sg[k];
        else               v = 0.0f;
        kesgw[i] = f2b(v);
    }
    else if (idx < n2) { int i = idx - n1; pi2w[i] = f2b(pi2[i]); }
    else if (idx < n3) { int i = idx - n2; cpw[i]  = f2b(cp[i]); }
    else if (idx < n4) { int i = idx - n3; sk0w[i] = f2b(sk0[i]); }
    else if (idx < n5) { int i = idx - n4; sk2w[i] = f2b(sk2[i]); }
    else if (idx < n6) { int i = idx - n5; m1ow[i] = f2b(m1o[i]); }
    else if (idx < n7) { int i = idx - n6; o1w[i]  = f2b(o1[i]); }
    else if (idx < n8) { int i = idx - n7; o2w[i]  = f2b(o2[i]); }
    else if (idx < n9) {
        int i = idx - n8;
        const float* s = (i < 512) ? tw_b : (i < 1024) ? pi0_b : (i < 1536) ? m1v_b : (i < 2048) ? mag_b : qo_b;
        bcat1[i] = s[i & 511];
    } else if (idx < n10) {
        int i = idx - n9;
        kesgb[i] = (i < 128) ? ke_b[i] : (i < 136) ? ve_b[i - 128] : (i == 136) ? sg_b[0] : 0.0f;
    }
}

// cast x (fp32 B,L,D) -> xcat bf16 (BL x 1024), cols [0,512)
__global__ __launch_bounds__(256)
void cast_x(const float* __restrict__ x, u16* __restrict__ xcat)
{
    int idx = blockIdx.x * 256 + threadIdx.x;   // over BL*512
    int c = idx & 511; int m = idx >> 9;
    xcat[(size_t)m * 1024 + c] = f2b(x[idx]);
}

// depthwise causal conv (K=4) gated branch: out = (conv_lc) * sigmoid(conv_cg), bf16
__global__ __launch_bounds__(256)
void conv_gate(const float* __restrict__ x,
               const float* __restrict__ lcw, const float* __restrict__ lcb,
               const float* __restrict__ cgw, const float* __restrict__ cgb,
               u16* __restrict__ out)
{
    int idx = blockIdx.x * 256 + threadIdx.x;   // over BL*512
    int d = idx & 511; int bl = idx >> 9;
    int l = bl & (L_ - 1); int b = bl >> 11;
    float a0 = 0.f, a1 = 0.f;
#pragma unroll
    for (int k = 0; k < 4; k++) {
        int ls = l - 3 + k;
        if (ls >= 0) {
            float xv = x[((size_t)(b * L_ + ls)) * 512 + d];
            a0 += xv * lcw[d * 4 + k];
            a1 += xv * cgw[d * 4 + k];
        }
    }
    a0 += lcb[d];
    a1 = sigm(a1 + cgb[d]);
    out[idx] = f2b(a0 * a1);
}

// gelu on out1 pi0 slice -> pi0g bf16
__global__ __launch_bounds__(256)
void gelu_pi0(const u16* __restrict__ out1, u16* __restrict__ pi0g)
{
    int idx = blockIdx.x * 256 + threadIdx.x;   // BL*512
    int c = idx & 511; int m = idx >> 9;
    float v = b2f(out1[(size_t)m * 2560 + 512 + c]);
    pi0g[idx] = f2b(gelu_f(v));
}

// ---------------------------------------------------------------------------
// Chunked scans over L.  Grid: 512 blocks = b(4) x dt(8) x nc(16); block 256 =
// dl(64 lanes over d) x lg(4 groups of 32 l's).  Chunk = 128 l's.
// ---------------------------------------------------------------------------
__global__ __launch_bounds__(256)
void scan_a(const u16* __restrict__ out1, const float* __restrict__ x,
            const float* __restrict__ oscale, const float* __restrict__ msc,
            float* __restrict__ cs_o, float* __restrict__ cs_x, float* __restrict__ cs_m)
{
    int blk = blockIdx.x;
    int nc = blk & 15, dt = (blk >> 4) & 7, b = blk >> 7;
    int t = threadIdx.x; int dl = t & 63, lg = t >> 6;
    int d = dt * 64 + dl;
    float os = fabsf(oscale[d]);
    float ms = fabsf(msc[0]);
    float so = 0.f, sx = 0.f, sm = 0.f;
    int l0 = nc * 128 + lg * 32;
    for (int i = 0; i < 32; i++) {
        size_t r = (size_t)(b * L_ + l0 + i);
        so += b2f(out1[r * 2560 + d]) * os;
        sm += sigm(b2f(out1[r * 2560 + 1536 + d])) * ms;
        sx += x[r * 512 + d];
    }
    __shared__ float sh[3][4][64];
    sh[0][lg][dl] = so; sh[1][lg][dl] = sx; sh[2][lg][dl] = sm;
    __syncthreads();
    if (t < 64) {
        float a = 0.f, xx = 0.f, m = 0.f;
        for (int g = 0; g < 4; g++) { a += sh[0][g][t]; xx += sh[1][g][t]; m += sh[2][g][t]; }
        size_t o = ((size_t)(b * 16 + nc)) * 512 + dt * 64 + t;
        cs_o[o] = a; cs_x[o] = xx; cs_m[o] = m;
    }
}

__global__ __launch_bounds__(256)
void scan_ex3(float* __restrict__ a0, float* __restrict__ a1, float* __restrict__ a2)
{
    int t = blockIdx.x * 256 + threadIdx.x;   // 2048 lanes (b,d)
    int d = t & 511; int b = t >> 9;
    float r0 = 0.f, r1 = 0.f, r2 = 0.f;
    for (int nc = 0; nc < 16; nc++) {
        size_t o = ((size_t)(b * 16 + nc)) * 512 + d;
        float v0 = a0[o]; a0[o] = r0; r0 += v0;
        float v1 = a1[o]; a1[o] = r1; r1 += v1;
        float v2 = a2[o]; a2[o] = r2; r2 += v2;
    }
}

__global__ __launch_bounds__(256)
void scan_ex2(float* __restrict__ a0, float* __restrict__ a1)
{
    int t = blockIdx.x * 256 + threadIdx.x;
    int d = t & 511; int b = t >> 9;
    float r0 = 0.f, r1 = 0.f;
    for (int nc = 0; nc < 16; nc++) {
        size_t o = ((size_t)(b * 16 + nc)) * 512 + d;
        float v0 = a0[o]; a0[o] = r0; r0 += v0;
        float v1 = a1[o]; a1[o] = r1; r1 += v1;
    }
}

__global__ __launch_bounds__(256)
void scan_c(const u16* __restrict__ out1, const float* __restrict__ phib,
            const float* __restrict__ oscale, const float* __restrict__ msc,
            const float* __restrict__ cs_o,
            float* __restrict__ phi, float* __restrict__ cs_wc, float* __restrict__ cs_ws)
{
    int blk = blockIdx.x;
    int nc = blk & 15, dt = (blk >> 4) & 7, b = blk >> 7;
    int t = threadIdx.x; int dl = t & 63, lg = t >> 6;
    int d = dt * 64 + dl;
    float os = fabsf(oscale[d]);
    float ms = fabsf(msc[0]);
    int l0 = nc * 128 + lg * 32;
    float so = 0.f;
    for (int i = 0; i < 32; i++) {
        size_t r = (size_t)(b * L_ + l0 + i);
        so += b2f(out1[r * 2560 + d]) * os;
    }
    __shared__ float sh[4][64];
    __shared__ float shw[2][4][64];
    sh[lg][dl] = so;
    __syncthreads();
    float pre = cs_o[((size_t)(b * 16 + nc)) * 512 + d];
    for (int g = 0; g < lg; g++) pre += sh[g][dl];
    float cum = pre, swc = 0.f, sws = 0.f;
    for (int i = 0; i < 32; i++) {
        size_t r = (size_t)(b * L_ + l0 + i);
        cum += b2f(out1[r * 2560 + d]) * os;
        float ph = phib[r * 512 + d] + cum;
        phi[r * 512 + d] = ph;
        float mg = sigm(b2f(out1[r * 2560 + 1536 + d])) * ms;
        float wv = mg * b2f(out1[r * 2560 + 1024 + d]);
        float s, c; sincosf(ph, &s, &c);
        swc += wv * c; sws += wv * s;
    }
    shw[0][lg][dl] = swc; shw[1][lg][dl] = sws;
    __syncthreads();
    if (t < 64) {
        float a = 0.f, bb = 0.f;
        for (int g = 0; g < 4; g++) { a += shw[0][g][t]; bb += shw[1][g][t]; }
        size_t o = ((size_t)(b * 16 + nc)) * 512 + dt * 64 + t;
        cs_wc[o] = a; cs_ws[o] = bb;
    }
}

__global__ __launch_bounds__(256)
void scan_e(const u16* __restrict__ out1, const float* __restrict__ phi,
            const float* __restrict__ x, const float* __restrict__ msc,
            const float* __restrict__ cs_m, const float* __restrict__ cs_x,
            const float* __restrict__ cs_wc, const float* __restrict__ cs_ws,
            u16* __restrict__ posret, u16* __restrict__ xcat, u16* __restrict__ combined)
{
    int blk = blockIdx.x;
    int nc = blk & 15, dt = (blk >> 4) & 7, b = blk >> 7;
    int t = threadIdx.x; int dl = t & 63, lg = t >> 6;
    int d = dt * 64 + dl;
    float ms = fabsf(msc[0]);
    int l0 = nc * 128 + lg * 32;
    float sm = 0.f, swc = 0.f, sws = 0.f, sx = 0.f;
    for (int i = 0; i < 32; i++) {
        size_t r = (size_t)(b * L_ + l0 + i);
        float ph = phi[r * 512 + d];
        float mg = sigm(b2f(out1[r * 2560 + 1536 + d])) * ms;
        float wv = mg * b2f(out1[r * 2560 + 1024 + d]);
        float s, c; sincosf(ph, &s, &c);
        sm += mg; swc += wv * c; sws += wv * s; sx += x[r * 512 + d];
    }
    __shared__ float sh[4][4][64];
    sh[0][lg][dl] = sm; sh[1][lg][dl] = swc; sh[2][lg][dl] = sws; sh[3][lg][dl] = sx;
    __syncthreads();
    size_t co = ((size_t)(b * 16 + nc)) * 512 + d;
    float cm = cs_m[co], cwc = cs_wc[co], cws = cs_ws[co], cx = cs_x[co];
    for (int g = 0; g < lg; g++) {
        cm += sh[0][g][dl]; cwc += sh[1][g][dl]; cws += sh[2][g][dl]; cx += sh[3][g][dl];
    }
    const float invsqD = 0.044194173824159216f;  // 1/sqrt(512)
    for (int i = 0; i < 32; i++) {
        int l = l0 + i;
        size_t r = (size_t)(b * L_ + l);
        float ph = phi[r * 512 + d];
        float mg = sigm(b2f(out1[r * 2560 + 1536 + d])) * ms;
        float wv = mg * b2f(out1[r * 2560 + 1024 + d]);
        float xv = x[r * 512 + d];
        float s, c; sincosf(ph, &s, &c);
        cm += mg; cwc += wv * c; cws += wv * s; cx += xv;
        float smag = sqrtf(cm + 1e-8f);
        float m1c = cwc / smag, m1s = cws / smag;
        float phq = ph + b2f(out1[r * 2560 + 2048 + d]);
        float sq, cq; sincosf(phq, &sq, &cq);
        float pr = (m1c * cq + m1s * sq) * invsqD;
        posret[r * 512 + d] = f2b(pr);
        xcat[r * 1024 + 512 + d] = f2b(cx / (float)(l + 1));
        combined[r * 2560 + 1536 + d] = f2b(xv * c);
        combined[r * 2560 + 2048 + d] = f2b(xv * s);
    }
}

// store-gate scan + gated values.  Grid 4 (b), block 256, 8 l's per thread.
__global__ __launch_bounds__(256)
void gate_scan(const float* __restrict__ kesgo, float* __restrict__ gni, float* __restrict__ gv)
{
    int b = blockIdx.x; int t = threadIdx.x;
    float sg[8]; float s = 0.f;
#pragma unroll
    for (int i = 0; i < 8; i++) {
        int l = t * 8 + i;
        float v = sigm(kesgo[((size_t)(b * L_ + l)) * 144 + 136]);
        sg[i] = v; s += v;
    }
    __shared__ float sh[256];
    sh[t] = s;
    __syncthreads();
    for (int ofs = 1; ofs < 256; ofs <<= 1) {
        float v = (t >= ofs) ? sh[t - ofs] : 0.f;
        __syncthreads();
        sh[t] += v;
        __syncthreads();
    }
    float cum = sh[t] - s;  // exclusive
#pragma unroll
    for (int i = 0; i < 8; i++) {
        int l = t * 8 + i;
        cum += sg[i];
        gni[b * L_ + l] = rsqrtf(fmaxf(cum, 1.0f)) * 1.0f;
        size_t r = (size_t)(b * L_ + l);
        for (int v = 0; v < 8; v++)
            gv[r * 8 + v] = kesgo[r * 144 + 128 + v] * sg[i];
    }
}

// KV chunk-state sums.  Grid B*64 (b,nc), block 64: lane t covers p=t,p=t+64.
__global__ void kv_chunk(const float* __restrict__ sppre, const float* __restrict__ gv,
                         float* __restrict__ csum)
{
    int blk = blockIdx.x; int nc = blk & 63, b = blk >> 6;
    int t = threadIdx.x;
    float Sc[2][8] = {}, Ss[2][8] = {};
    for (int i = 0; i < 32; i++) {
        size_t r = (size_t)(b * L_ + nc * 32 + i);
        float g[8];
#pragma unroll
        for (int v = 0; v < 8; v++) g[v] = gv[r * 8 + v];
#pragma unroll
        for (int j = 0; j < 2; j++) {
            float sp = tanhf(sppre[r * 128 + t + j * 64]) * PI_F;
            float s, c; sincosf(sp, &s, &c);
#pragma unroll
            for (int v = 0; v < 8; v++) { Sc[j][v] += c * g[v]; Ss[j][v] += s * g[v]; }
        }
    }
    size_t base = (size_t)blk * 2048;
#pragma unroll
    for (int j = 0; j < 2; j++)
#pragma unroll
        for (int v = 0; v < 8; v++) {
            csum[base + (t + j * 64) * 8 + v]        = Sc[j][v];
            csum[base + 1024 + (t + j * 64) * 8 + v] = Ss[j][v];
        }
}

// exclusive scan of chunk states over nc.  8192 lanes.
__global__ __launch_bounds__(256)
void kv_scan(float* __restrict__ csum)
{
    int t = blockIdx.x * 256 + threadIdx.x;   // (b, cs, pv)
    int pv = t & 1023; int cs = (t >> 10) & 1; int b = t >> 11;
    float run = 0.f;
    for (int nc = 0; nc < 64; nc++) {
        size_t o = ((size_t)(b * 64 + nc)) * 2048 + cs * 1024 + pv;
        float v = csum[o]; csum[o] = run; run += v;
    }
}

// KV retrieve: walk chunk inclusively, butterfly-reduce over P.
__global__ void kv_retrieve(const float* __restrict__ sppre, const float* __restrict__ kesgo,
                            const float* __restrict__ gv, const float* __restrict__ gni,
                            const float* __restrict__ csum, float* __restrict__ kvr)
{
    int blk = blockIdx.x; int nc = blk & 63, b = blk >> 6;
    int t = threadIdx.x;
    float Sc[2][8], Ss[2][8];
    size_t base = (size_t)blk * 2048;
#pragma unroll
    for (int j = 0; j < 2; j++)
#pragma unroll
        for (int v = 0; v < 8; v++) {
            Sc[j][v] = csum[base + (t + j * 64) * 8 + v];
            Ss[j][v] = csum[base + 1024 + (t + j * 64) * 8 + v];
        }
    for (int i = 0; i < 32; i++) {
        size_t r = (size_t)(b * L_ + nc * 32 + i);
        float g[8];
#pragma unroll
        for (int v = 0; v < 8; v++) g[v] = gv[r * 8 + v];
        float part[8];
#pragma unroll
        for (int v = 0; v < 8; v++) part[v] = 0.f;
#pragma unroll
        for (int j = 0; j < 2; j++) {
            float sp = tanhf(sppre[r * 128 + t + j * 64]) * PI_F;
            float s, c; sincosf(sp, &s, &c);
#pragma unroll
            for (int v = 0; v < 8; v++) { Sc[j][v] += c * g[v]; Ss[j][v] += s * g[v]; }
            float qp = tanhf(kesgo[r * 144 + t + j * 64]) * PI_F;
            float sq, cq; sincosf(qp, &sq, &cq);
#pragma unroll
            for (int v = 0; v < 8; v++) part[v] += cq * Sc[j][v] + sq * Ss[j][v];
        }
#pragma unroll
        for (int ofs = 1; ofs < 64; ofs <<= 1)
#pragma unroll
            for (int v = 0; v < 8; v++) part[v] += __shfl_xor(part[v], ofs, 64);
        if (t == 0) {
            float sc = gni[r] * 0.08838834764831845f;   // 1/sqrt(128)
#pragma unroll
            for (int v = 0; v < 8; v++) kvr[r * 8 + v] = part[v] * sc;
        }
    }
}

// kv_out linear (K=8) into combined cols [1024,1536), bf16
__global__ __launch_bounds__(256)
void kvo_lin(const float* __restrict__ kvr, const float* __restrict__ w,
             const float* __restrict__ bias, u16* __restrict__ combined)
{
    int idx = blockIdx.x * 256 + threadIdx.x;   // BL*512
    int n = idx & 511; size_t m = idx >> 9;
    float acc = bias[n];
#pragma unroll
    for (int k = 0; k < 8; k++) acc += kvr[m * 8 + k] * w[n * 8 + k];
    combined[m * 2560 + 1024 + n] = f2b(acc);
}

// layernorm over 2560, in place on bf16 combined
__global__ __launch_bounds__(256)
void ln_rows(u16* __restrict__ combined, const float* __restrict__ g, const float* __restrict__ bb)
{
    size_t m = blockIdx.x; int t = threadIdx.x;
    float v[10]; float s = 0.f, s2 = 0.f;
#pragma unroll
    for (int i = 0; i < 10; i++) {
        float x = b2f(combined[m * 2560 + t + i * 256]);
        v[i] = x; s += x; s2 += x * x;
    }
    __shared__ float sh[2][256];
    sh[0][t] = s; sh[1][t] = s2;
    __syncthreads();
    for (int ofs = 128; ofs > 0; ofs >>= 1) {
        if (t < ofs) { sh[0][t] += sh[0][t + ofs]; sh[1][t] += sh[1][t + ofs]; }
        __syncthreads();
    }
    float mean = sh[0][0] * (1.0f / 2560.0f);
    float var  = sh[1][0] * (1.0f / 2560.0f) - mean * mean;
    float rstd = rsqrtf(var + 1e-5f);
#pragma unroll
    for (int i = 0; i < 10; i++) {
        int c = t + i * 256;
        combined[m * 2560 + c] = f2b((v[i] - mean) * rstd * g[c] + bb[c]);
    }
}

// ---------------------------------------------------------------------------
extern "C" void kernel_launch(void* const* d_in, const int* in_sizes, int n_in,
                              void* d_out, int out_size, void* d_ws, size_t ws_size,
                              hipStream_t stream)
{
    const float* x     = (const float*)d_in[0];
    const float* lc_w  = (const float*)d_in[1];
    const float* lc_b  = (const float*)d_in[2];
    const float* cg_w  = (const float*)d_in[3];
    const float* cg_b  = (const float*)d_in[4];
    const float* cp_w  = (const float*)d_in[5];
    const float* cp_b  = (const float*)d_in[6];
    const float* tw_w  = (const float*)d_in[7];
    const float* tw_b  = (const float*)d_in[8];
    const float* omega_scale = (const float*)d_in[9];
    const float* pi0_w = (const float*)d_in[10];
    const float* pi0_b = (const float*)d_in[11];
    const float* pi2_w = (const float*)d_in[12];
    const float* pi2_b = (const float*)d_in[13];
    const float* m1v_w = (const float*)d_in[14];
    const float* m1v_b = (const float*)d_in[15];
    const float* m1o_w = (const float*)d_in[16];
    const float* m1o_b = (const float*)d_in[17];
    const float* mag_w = (const float*)d_in[18];
    const float* mag_b = (const float*)d_in[19];
    const float* mag_scale = (const float*)d_in[20];
    const float* qo_w  = (const float*)d_in[21];
    const float* qo_b  = (const float*)d_in[22];
    const float* ke_w  = (const float*)d_in[23];
    const float* ke_b  = (const float*)d_in[24];
    const float* ve_w  = (const float*)d_in[25];
    const float* ve_b  = (const float*)d_in[26];
    const float* sk0_w = (const float*)d_in[27];
    const float* sk0_b = (const float*)d_in[28];
    const float* sk2_w = (const float*)d_in[29];
    const float* sk2_b = (const float*)d_in[30];
    const float* sg_w  = (const float*)d_in[31];
    const float* sg_b  = (const float*)d_in[32];
    const float* kvo_w = (const float*)d_in[33];
    const float* kvo_b = (const float*)d_in[34];
    const float* ln_g  = (const float*)d_in[35];
    const float* ln_b  = (const float*)d_in[36];
    const float* o1_w  = (const float*)d_in[37];
    const float* o1_b  = (const float*)d_in[38];
    const float* o2_w  = (const float*)d_in[39];
    const float* o2_b  = (const float*)d_in[40];
    float* out = (float*)d_out;

    char* base = (char*)d_ws;
    size_t off = 0;
    auto alloc = [&](size_t bytes) -> void* {
        void* p = base + off;
        off += (bytes + 255) & ~(size_t)255;
        return p;
    };

    u16*   wcat1  = (u16*)  alloc((size_t)2560 * 512 * 2);
    float* bcat1  = (float*)alloc(2560 * 4);
    u16*   kesgw  = (u16*)  alloc((size_t)256 * 512 * 2);
    float* kesgb  = (float*)alloc(256 * 4);
    u16*   pi2w   = (u16*)  alloc((size_t)512 * 512 * 2);
    u16*   cpw    = (u16*)  alloc((size_t)512 * 512 * 2);
    u16*   sk0w   = (u16*)  alloc((size_t)512 * 1024 * 2);
    u16*   sk2w   = (u16*)  alloc((size_t)128 * 512 * 2);
    u16*   m1ow   = (u16*)  alloc((size_t)512 * 512 * 2);
    u16*   o1w    = (u16*)  alloc((size_t)1024 * 2560 * 2);
    u16*   o2w    = (u16*)  alloc((size_t)512 * 1024 * 2);
    u16*   xcat   = (u16*)  alloc((size_t)BL * 1024 * 2);
    u16*   out1   = (u16*)  alloc((size_t)BL * 2560 * 2);
    u16*   pi0g   = (u16*)  alloc((size_t)BL * 512 * 2);
    float* phib   = (float*)alloc((size_t)BL * 512 * 4);
    float* phi    = (float*)alloc((size_t)BL * 512 * 4);
    float* kesgo  = (float*)alloc((size_t)BL * 144 * 4);
    u16*   convg  = (u16*)  alloc((size_t)BL * 512 * 2);
    u16*   posret = (u16*)  alloc((size_t)BL * 512 * 2);
    u16*   sk0g   = (u16*)  alloc((size_t)BL * 512 * 2);
    float* sppre  = (float*)alloc((size_t)BL * 128 * 4);
    u16*   combined = (u16*)alloc((size_t)BL * 2560 * 2);
    u16*   o1g    = (u16*)  alloc((size_t)BL * 1024 * 2);
    float* cs_o   = (float*)alloc((size_t)4 * 16 * 512 * 4);
    float* cs_x   = (float*)alloc((size_t)4 * 16 * 512 * 4);
    float* cs_m   = (float*)alloc((size_t)4 * 16 * 512 * 4);
    float* cs_wc  = (float*)alloc((size_t)4 * 16 * 512 * 4);
    float* cs_ws  = (float*)alloc((size_t)4 * 16 * 512 * 4);
    float* gni    = (float*)alloc((size_t)BL * 4);
    float* gv     = (float*)alloc((size_t)BL * 8 * 4);
    float* kvcs   = (float*)alloc((size_t)4 * 64 * 2048 * 4);
    float* kvr    = (float*)alloc((size_t)BL * 8 * 4);
    (void)ws_size; (void)in_sizes; (void)n_in; (void)out_size;

    // 1. weight prep
    prep_weights<<<23307, 256, 0, stream>>>(
        tw_w, pi0_w, m1v_w, mag_w, qo_w, ke_w, ve_w, sg_w,
        pi2_w, cp_w, sk0_w, sk2_w, m1o_w, o1_w, o2_w,
        tw_b, pi0_b, m1v_b, mag_b, qo_b, ke_b, ve_b, sg_b,
        wcat1, bcat1, kesgw, kesgb, pi2w, cpw, sk0w, sk2w, m1ow, o1w, o2w);
    // 2. cast x
    cast_x<<<16384, 256, 0, stream>>>(x, xcat);
    // 3. conv branch input
    conv_gate<<<16384, 256, 0, stream>>>(x, lc_w, lc_b, cg_w, cg_b, convg);
    // 4. pass-1 fused GEMM: [omega | pi0 | v1 | mag | qoff]
    gemm_bt<EPI_BF16><<<dim3(64, 20), 256, 0, stream>>>(xcat, 1024, wcat1, bcat1,
                                                        out1, 2560, 2560, 512, nullptr);
    // 5. gelu(pi0)
    gelu_pi0<<<16384, 256, 0, stream>>>(out1, pi0g);
    // 6. pi2 -> phi_base
    gemm_bt<EPI_F32><<<dim3(64, 4), 256, 0, stream>>>(pi0g, 512, pi2w, pi2_b,
                                                      phib, 512, 512, 512, nullptr);
    // 7. ke/ve/sg fused GEMM
    gemm_bt<EPI_F32><<<dim3(64, 2), 256, 0, stream>>>(xcat, 1024, kesgw, kesgb,
                                                      kesgo, 144, 144, 512, nullptr);
    // 8-12. chunked scans (phi, magnitude memory, context_avg)
    scan_a<<<512, 256, 0, stream>>>(out1, x, omega_scale, mag_scale, cs_o, cs_x, cs_m);
    scan_ex3<<<8, 256, 0, stream>>>(cs_o, cs_x, cs_m);
    scan_c<<<512, 256, 0, stream>>>(out1, phib, omega_scale, mag_scale, cs_o, phi, cs_wc, cs_ws);
    scan_ex2<<<8, 256, 0, stream>>>(cs_wc, cs_ws);
    scan_e<<<512, 256, 0, stream>>>(out1, phi, x, mag_scale, cs_m, cs_x, cs_wc, cs_ws,
                                    posret, xcat, combined);
    // 13. store-gate scan + gated values
    gate_scan<<<4, 256, 0, stream>>>(kesgo, gni, gv);
    // 14. sk0 (gelu) on [x | context_avg]
    gemm_bt<EPI_GELU_BF16><<<dim3(64, 4), 256, 0, stream>>>(xcat, 1024, sk0w, sk0_b,
                                                            sk0g, 512, 512, 1024, nullptr);
    // 15. sk2 -> storage phase pre-tanh
    gemm_bt<EPI_F32><<<dim3(64, 1), 256, 0, stream>>>(sk0g, 512, sk2w, sk2_b,
                                                      sppre, 128, 128, 512, nullptr);
    // 16-18. KV memory
    kv_chunk<<<256, 64, 0, stream>>>(sppre, gv, kvcs);
    kv_scan<<<32, 256, 0, stream>>>(kvcs);
    kv_retrieve<<<256, 64, 0, stream>>>(sppre, kesgo, gv, gni, kvcs, kvr);
    // 19. kv_out linear
    kvo_lin<<<16384, 256, 0, stream>>>(kvr, kvo_w, kvo_b, combined);
    // 20. conv projection -> combined[:, 0:512)
    gemm_bt<EPI_BF16><<<dim3(64, 4), 256, 0, stream>>>(convg, 512, cpw, cp_b,
                                                       combined, 2560, 512, 512, nullptr);
    // 21. pos_out -> combined[:, 512:1024)
    gemm_bt<EPI_BF16><<<dim3(64, 4), 256, 0, stream>>>(posret, 512, m1ow, m1o_b,
                                                       combined + 512, 2560, 512, 512, nullptr);
    // 22. layernorm in place
    ln_rows<<<8192, 256, 0, stream>>>(combined, ln_g, ln_b);
    // 23. o1 + gelu
    gemm_bt<EPI_GELU_BF16><<<dim3(64, 8), 256, 0, stream>>>(combined, 2560, o1w, o1_b,
                                                            o1g, 1024, 1024, 2560, nullptr);
    // 24. o2 + residual -> out
    gemm_bt<EPI_RESID_F32><<<dim3(64, 4), 256, 0, stream>>>(o1g, 1024, o2w, o2_b,
                                                            out, 512, 512, 1024, x);
}

// Round 2
// 658.969 us; speedup vs baseline: 1.0550x; 1.0550x over previous
//
#include <hip/hip_runtime.h>
#include <cstdint>

typedef unsigned short u16;
typedef short short8 __attribute__((ext_vector_type(8)));
typedef float floatx4 __attribute__((ext_vector_type(4)));

#define B_ 4
#define L_ 2048
#define D_ 512
#define P_ 128
#define V_ 8
#define BL (B_ * L_)        // 8192
#define NC_ 128             // KV chunks per batch
#define CH_ 16              // KV chunk length
#define PI_F 3.14159265358979323846f

__device__ inline u16 f2b(float f) {
    unsigned u = __float_as_uint(f);
    unsigned r = u + 0x7FFFu + ((u >> 16) & 1u);
    return (u16)(r >> 16);
}
__device__ inline float b2f(u16 h) {
    return __uint_as_float(((unsigned)h) << 16);
}
__device__ inline float gelu_f(float v) {
    return 0.5f * v * (1.0f + erff(v * 0.70710678118654752f));
}
__device__ inline float sigm(float v) {
    return 1.0f / (1.0f + expf(-v));
}

// async global->LDS, 16B per lane. LDS dest is wave-uniform base + lane*16.
__device__ inline void async16(const u16* g, u16* l) {
    __builtin_amdgcn_global_load_lds(
        (const __attribute__((address_space(1))) unsigned int*)g,
        (__attribute__((address_space(3))) unsigned int*)l, 16, 0, 0);
}

// ---------------------------------------------------------------------------
// m97-style bf16 MFMA GEMM: C[m,n] = epi( sum_k A[m,k]*W[n,k] + bias[n] )
// A: (M x K) bf16 row-major (lda elems), W: (Npad x K) bf16 row-major,
// M multiple of 128, K multiple of 32.
// ---------------------------------------------------------------------------
enum { EPI_F32 = 0, EPI_BF16 = 1, EPI_GELU_BF16 = 2, EPI_RESID_F32 = 3, EPI_PASS1 = 4 };

template <int EPI>
__global__ __launch_bounds__(256)
void gemm_bt(const u16* __restrict__ A, int lda,
             const u16* __restrict__ W,
             const float* __restrict__ bias,
             void* __restrict__ Cout, int ldc,
             int N, int K,
             const float* __restrict__ resid)
{
    __shared__ u16 As[128 * 32];   // unpadded: required by global_load_lds lane order
    __shared__ u16 Bs[128 * 32];
    const int tid  = threadIdx.x;
    const int mt   = blockIdx.x, nt = blockIdx.y;
    const int lane = tid & 63;
    const int wid  = tid >> 6;          // 0..3
    const int wm   = wid & 1, wn = wid >> 1;
    const int l16  = lane & 15, quad = lane >> 4;

    floatx4 acc[4][4] = {};

    const u16* Ab = A + (size_t)(mt * 128) * lda;
    const u16* Wb = W + (size_t)(nt * 128) * K;

    // staging: wave wid covers rows [wid*16, wid*16+16) (slot 0) and +64 (slot 1);
    // lane -> row = lane/4, col = (lane&3)*8 within the slot (16B per lane).
    const int srow = lane >> 2;
    const int scol = (lane & 3) * 8;
    const u16* ga0 = Ab + (size_t)(wid * 16 + srow) * lda + scol;
    const u16* ga1 = Ab + (size_t)(64 + wid * 16 + srow) * lda + scol;
    const u16* gb0 = Wb + (size_t)(wid * 16 + srow) * K + scol;
    const u16* gb1 = Wb + (size_t)(64 + wid * 16 + srow) * K + scol;
    u16* la0 = &As[(wid * 16) * 32];        // wave-uniform LDS bases
    u16* la1 = &As[(64 + wid * 16) * 32];
    u16* lb0 = &Bs[(wid * 16) * 32];
    u16* lb1 = &Bs[(64 + wid * 16) * 32];

    for (int k0 = 0; k0 < K; k0 += 32) {
        __syncthreads();
        async16(ga0 + k0, la0);
        async16(ga1 + k0, la1);
        async16(gb0 + k0, lb0);
        async16(gb1 + k0, lb1);
        __syncthreads();    // compiler emits s_waitcnt vmcnt(0) before s_barrier
        short8 a[4], b[4];
#pragma unroll
        for (int i = 0; i < 4; i++)
            a[i] = *(const short8*)(&As[(wm * 64 + i * 16 + l16) * 32 + quad * 8]);
#pragma unroll
        for (int j = 0; j < 4; j++)
            b[j] = *(const short8*)(&Bs[(wn * 64 + j * 16 + l16) * 32 + quad * 8]);
#pragma unroll
        for (int i = 0; i < 4; i++)
#pragma unroll
            for (int j = 0; j < 4; j++)
                acc[i][j] = __builtin_amdgcn_mfma_f32_16x16x32_bf16(a[i], b[j], acc[i][j], 0, 0, 0);
    }

#pragma unroll
    for (int i = 0; i < 4; i++) {
#pragma unroll
        for (int j = 0; j < 4; j++) {
#pragma unroll
            for (int r = 0; r < 4; r++) {
                int grow = mt * 128 + wm * 64 + i * 16 + quad * 4 + r;
                int gcol = nt * 128 + wn * 64 + j * 16 + l16;
                if (gcol < N) {
                    float v = acc[i][j][r] + bias[gcol];
                    size_t off = (size_t)grow * ldc + gcol;
                    if (EPI == EPI_F32)            ((float*)Cout)[off] = v;
                    else if (EPI == EPI_BF16)      ((u16*)Cout)[off] = f2b(v);
                    else if (EPI == EPI_GELU_BF16) ((u16*)Cout)[off] = f2b(gelu_f(v));
                    else if (EPI == EPI_PASS1) {
                        float vv = (gcol >= 512 && gcol < 1024) ? gelu_f(v) : v;
                        ((u16*)Cout)[off] = f2b(vv);
                    }
                    else                           ((float*)Cout)[off] = v + resid[off];
                }
            }
        }
    }
}

// ---------------------------------------------------------------------------
// Weight prep: cast fp32 weights -> bf16, build concatenations + pads.
// ---------------------------------------------------------------------------
__global__ __launch_bounds__(256)
void prep_weights(const float* tw, const float* pi0, const float* m1v, const float* mag, const float* qo,
                  const float* ke, const float* ve, const float* sg,
                  const float* pi2, const float* cp, const float* sk0, const float* sk2,
                  const float* m1o, const float* o1, const float* o2,
                  const float* tw_b, const float* pi0_b, const float* m1v_b, const float* mag_b, const float* qo_b,
                  const float* ke_b, const float* ve_b, const float* sg_b,
                  u16* wcat1, float* bcat1, u16* kesgw, float* kesgb,
                  u16* pi2w, u16* cpw, u16* sk0w, u16* sk2w, u16* m1ow, u16* o1w, u16* o2w)
{
    int idx = blockIdx.x * 256 + threadIdx.x;
    const int n0 = 2560 * 512;
    const int n1 = n0 + 256 * 512;
    const int n2 = n1 + 512 * 512;
    const int n3 = n2 + 512 * 512;
    const int n4 = n3 + 512 * 1024;
    const int n5 = n4 + 128 * 512;
    const int n6 = n5 + 512 * 512;
    const int n7 = n6 + 1024 * 2560;
    const int n8 = n7 + 512 * 1024;
    const int n9 = n8 + 2560;
    const int n10 = n9 + 256;
    if (idx < n0) {
        int r = idx >> 9, k = idx & 511;
        const float* s = (r < 512) ? tw : (r < 1024) ? pi0 : (r < 1536) ? m1v : (r < 2048) ? mag : qo;
        wcat1[idx] = f2b(s[(r & 511) * 512 + k]);
    } else if (idx < n1) {
        int i = idx - n0; int r = i >> 9, k = i & 511;
        float v;
        if (r < 128)      v = ke[r * 512 + k];
        else if (r < 136) v = ve[(r - 128) * 512 + k];
        else if (r == 136) v = sg[k];
        else               v = 0.0f;
        kesgw[i] = f2b(v);
    }
    else if (idx < n2) { int i = idx - n1; pi2w[i] = f2b(pi2[i]); }
    else if (idx < n3) { int i = idx - n2; cpw[i]  = f2b(cp[i]); }
    else if (idx < n4) { int i = idx - n3; sk0w[i] = f2b(sk0[i]); }
    else if (idx < n5) { int i = idx - n4; sk2w[i] = f2b(sk2[i]); }
    else if (idx < n6) { int i = idx - n5; m1ow[i] = f2b(m1o[i]); }
    else if (idx < n7) { int i = idx - n6; o1w[i]  = f2b(o1[i]); }
    else if (idx < n8) { int i = idx - n7; o2w[i]  = f2b(o2[i]); }
    else if (idx < n9) {
        int i = idx - n8;
        const float* s = (i < 512) ? tw_b : (i < 1024) ? pi0_b : (i < 1536) ? m1v_b : (i < 2048) ? mag_b : qo_b;
        bcat1[i] = s[i & 511];
    } else if (idx < n10) {
        int i = idx - n9;
        kesgb[i] = (i < 128) ? ke_b[i] : (i < 136) ? ve_b[i - 128] : (i == 136) ? sg_b[0] : 0.0f;
    }
}

// depthwise causal conv (K=4) gated branch + cast x into xcat cols [0,512)
__global__ __launch_bounds__(256)
void conv_gate(const float* __restrict__ x,
               const float* __restrict__ lcw, const float* __restrict__ lcb,
               const float* __restrict__ cgw, const float* __restrict__ cgb,
               u16* __restrict__ out, u16* __restrict__ xcat)
{
    int idx = blockIdx.x * 256 + threadIdx.x;   // over BL*512
    int d = idx & 511; int bl = idx >> 9;
    int l = bl & (L_ - 1); int b = bl >> 11;
    float a0 = 0.f, a1 = 0.f, xv3 = 0.f;
#pragma unroll
    for (int k = 0; k < 4; k++) {
        int ls = l - 3 + k;
        if (ls >= 0) {
            float xv = x[((size_t)(b * L_ + ls)) * 512 + d];
            if (k == 3) xv3 = xv;
            a0 += xv * lcw[d * 4 + k];
            a1 += xv * cgw[d * 4 + k];
        }
    }
    a0 += lcb[d];
    a1 = sigm(a1 + cgb[d]);
    out[idx] = f2b(a0 * a1);
    xcat[(size_t)bl * 1024 + d] = f2b(xv3);
}

// ---------------------------------------------------------------------------
// Chunked scans over L.  Grid: 512 blocks = b(4) x dt(8) x nc(16); block 256 =
// dl(64 lanes over d) x lg(4 groups of 32 l's).  Chunk = 128 l's.
// ---------------------------------------------------------------------------
__global__ __launch_bounds__(256)
void scan_a(const u16* __restrict__ out1, const float* __restrict__ x,
            const float* __restrict__ oscale, const float* __restrict__ msc,
            float* __restrict__ cs_o, float* __restrict__ cs_x, float* __restrict__ cs_m)
{
    int blk = blockIdx.x;
    int nc = blk & 15, dt = (blk >> 4) & 7, b = blk >> 7;
    int t = threadIdx.x; int dl = t & 63, lg = t >> 6;
    int d = dt * 64 + dl;
    float os = fabsf(oscale[d]);
    float ms = fabsf(msc[0]);
    float so = 0.f, sx = 0.f, sm = 0.f;
    int l0 = nc * 128 + lg * 32;
    for (int i = 0; i < 32; i++) {
        size_t r = (size_t)(b * L_ + l0 + i);
        so += b2f(out1[r * 2560 + d]) * os;
        sm += sigm(b2f(out1[r * 2560 + 1536 + d])) * ms;
        sx += x[r * 512 + d];
    }
    __shared__ float sh[3][4][64];
    sh[0][lg][dl] = so; sh[1][lg][dl] = sx; sh[2][lg][dl] = sm;
    __syncthreads();
    if (t < 64) {
        float a = 0.f, xx = 0.f, m = 0.f;
        for (int g = 0; g < 4; g++) { a += sh[0][g][t]; xx += sh[1][g][t]; m += sh[2][g][t]; }
        size_t o = ((size_t)(b * 16 + nc)) * 512 + dt * 64 + t;
        cs_o[o] = a; cs_x[o] = xx; cs_m[o] = m;
    }
}

__global__ __launch_bounds__(256)
void scan_ex3(float* __restrict__ a0, float* __restrict__ a1, float* __restrict__ a2)
{
    int t = blockIdx.x * 256 + threadIdx.x;   // 2048 lanes (b,d)
    int d = t & 511; int b = t >> 9;
    float r0 = 0.f, r1 = 0.f, r2 = 0.f;
    for (int nc = 0; nc < 16; nc++) {
        size_t o = ((size_t)(b * 16 + nc)) * 512 + d;
        float v0 = a0[o]; a0[o] = r0; r0 += v0;
        float v1 = a1[o]; a1[o] = r1; r1 += v1;
        float v2 = a2[o]; a2[o] = r2; r2 += v2;
    }
}

__global__ __launch_bounds__(256)
void scan_ex2(float* __restrict__ a0, float* __restrict__ a1)
{
    int t = blockIdx.x * 256 + threadIdx.x;
    int d = t & 511; int b = t >> 9;
    float r0 = 0.f, r1 = 0.f;
    for (int nc = 0; nc < 16; nc++) {
        size_t o = ((size_t)(b * 16 + nc)) * 512 + d;
        float v0 = a0[o]; a0[o] = r0; r0 += v0;
        float v1 = a1[o]; a1[o] = r1; r1 += v1;
    }
}

__global__ __launch_bounds__(256)
void scan_c(const u16* __restrict__ out1, const float* __restrict__ phib,
            const float* __restrict__ oscale, const float* __restrict__ msc,
            const float* __restrict__ cs_o,
            float* __restrict__ phi, float* __restrict__ cs_wc, float* __restrict__ cs_ws)
{
    int blk = blockIdx.x;
    int nc = blk & 15, dt = (blk >> 4) & 7, b = blk >> 7;
    int t = threadIdx.x; int dl = t & 63, lg = t >> 6;
    int d = dt * 64 + dl;
    float os = fabsf(oscale[d]);
    float ms = fabsf(msc[0]);
    int l0 = nc * 128 + lg * 32;
    float so = 0.f;
    for (int i = 0; i < 32; i++) {
        size_t r = (size_t)(b * L_ + l0 + i);
        so += b2f(out1[r * 2560 + d]) * os;
    }
    __shared__ float sh[4][64];
    __shared__ float shw[2][4][64];
    sh[lg][dl] = so;
    __syncthreads();
    float pre = cs_o[((size_t)(b * 16 + nc)) * 512 + d];
    for (int g = 0; g < lg; g++) pre += sh[g][dl];
    float cum = pre, swc = 0.f, sws = 0.f;
    for (int i = 0; i < 32; i++) {
        size_t r = (size_t)(b * L_ + l0 + i);
        cum += b2f(out1[r * 2560 + d]) * os;
        float ph = phib[r * 512 + d] + cum;
        phi[r * 512 + d] = ph;
        float mg = sigm(b2f(out1[r * 2560 + 1536 + d])) * ms;
        float wv = mg * b2f(out1[r * 2560 + 1024 + d]);
        float s, c; sincosf(ph, &s, &c);
        swc += wv * c; sws += wv * s;
    }
    shw[0][lg][dl] = swc; shw[1][lg][dl] = sws;
    __syncthreads();
    if (t < 64) {
        float a = 0.f, bb = 0.f;
        for (int g = 0; g < 4; g++) { a += shw[0][g][t]; bb += shw[1][g][t]; }
        size_t o = ((size_t)(b * 16 + nc)) * 512 + dt * 64 + t;
        cs_wc[o] = a; cs_ws[o] = bb;
    }
}

__global__ __launch_bounds__(256)
void scan_e(const u16* __restrict__ out1, const float* __restrict__ phi,
            const float* __restrict__ x, const float* __restrict__ msc,
            const float* __restrict__ cs_m, const float* __restrict__ cs_x,
            const float* __restrict__ cs_wc, const float* __restrict__ cs_ws,
            u16* __restrict__ posret, u16* __restrict__ xcat, u16* __restrict__ combined)
{
    int blk = blockIdx.x;
    int nc = blk & 15, dt = (blk >> 4) & 7, b = blk >> 7;
    int t = threadIdx.x; int dl = t & 63, lg = t >> 6;
    int d = dt * 64 + dl;
    float ms = fabsf(msc[0]);
    int l0 = nc * 128 + lg * 32;
    float sm = 0.f, swc = 0.f, sws = 0.f, sx = 0.f;
    for (int i = 0; i < 32; i++) {
        size_t r = (size_t)(b * L_ + l0 + i);
        float ph = phi[r * 512 + d];
        float mg = sigm(b2f(out1[r * 2560 + 1536 + d])) * ms;
        float wv = mg * b2f(out1[r * 2560 + 1024 + d]);
        float s, c; sincosf(ph, &s, &c);
        sm += mg; swc += wv * c; sws += wv * s; sx += x[r * 512 + d];
    }
    __shared__ float sh[4][4][64];
    sh[0][lg][dl] = sm; sh[1][lg][dl] = swc; sh[2][lg][dl] = sws; sh[3][lg][dl] = sx;
    __syncthreads();
    size_t co = ((size_t)(b * 16 + nc)) * 512 + d;
    float cm = cs_m[co], cwc = cs_wc[co], cws = cs_ws[co], cx = cs_x[co];
    for (int g = 0; g < lg; g++) {
        cm += sh[0][g][dl]; cwc += sh[1][g][dl]; cws += sh[2][g][dl]; cx += sh[3][g][dl];
    }
    const float invsqD = 0.044194173824159216f;  // 1/sqrt(512)
    for (int i = 0; i < 32; i++) {
        int l = l0 + i;
        size_t r = (size_t)(b * L_ + l);
        float ph = phi[r * 512 + d];
        float mg = sigm(b2f(out1[r * 2560 + 1536 + d])) * ms;
        float wv = mg * b2f(out1[r * 2560 + 1024 + d]);
        float xv = x[r * 512 + d];
        float s, c; sincosf(ph, &s, &c);
        cm += mg; cwc += wv * c; cws += wv * s; cx += xv;
        float smag = sqrtf(cm + 1e-8f);
        float m1c = cwc / smag, m1s = cws / smag;
        float phq = ph + b2f(out1[r * 2560 + 2048 + d]);
        float sq, cq; sincosf(phq, &sq, &cq);
        float pr = (m1c * cq + m1s * sq) * invsqD;
        posret[r * 512 + d] = f2b(pr);
        xcat[r * 1024 + 512 + d] = f2b(cx / (float)(l + 1));
        combined[r * 2560 + 1536 + d] = f2b(xv * c);
        combined[r * 2560 + 2048 + d] = f2b(xv * s);
    }
}

// store-gate scan + gated values.  Grid 4 (b), block 256, 8 l's per thread.
__global__ __launch_bounds__(256)
void gate_scan(const float* __restrict__ kesgo, float* __restrict__ gni, float* __restrict__ gv)
{
    int b = blockIdx.x; int t = threadIdx.x;
    float sg[8]; float s = 0.f;
#pragma unroll
    for (int i = 0; i < 8; i++) {
        int l = t * 8 + i;
        float v = sigm(kesgo[((size_t)(b * L_ + l)) * 144 + 136]);
        sg[i] = v; s += v;
    }
    __shared__ float sh[256];
    sh[t] = s;
    __syncthreads();
    for (int ofs = 1; ofs < 256; ofs <<= 1) {
        float v = (t >= ofs) ? sh[t - ofs] : 0.f;
        __syncthreads();
        sh[t] += v;
        __syncthreads();
    }
    float cum = sh[t] - s;  // exclusive
#pragma unroll
    for (int i = 0; i < 8; i++) {
        int l = t * 8 + i;
        cum += sg[i];
        gni[b * L_ + l] = rsqrtf(fmaxf(cum, 1.0f));
        size_t r = (size_t)(b * L_ + l);
        for (int v = 0; v < 8; v++)
            gv[r * 8 + v] = kesgo[r * 144 + 128 + v] * sg[i];
    }
}

// KV chunk-state sums.  Grid B*NC_ (b,nc), block 64: lane t covers p=t,p=t+64.
__global__ void kv_chunk(const float* __restrict__ sppre, const float* __restrict__ gv,
                         float* __restrict__ csum)
{
    int blk = blockIdx.x; int nc = blk & (NC_ - 1), b = blk >> 7;
    int t = threadIdx.x;
    float Sc[2][8] = {}, Ss[2][8] = {};
    for (int i = 0; i < CH_; i++) {
        size_t r = (size_t)(b * L_ + nc * CH_ + i);
        float g[8];
#pragma unroll
        for (int v = 0; v < 8; v++) g[v] = gv[r * 8 + v];
#pragma unroll
        for (int j = 0; j < 2; j++) {
            float sp = tanhf(sppre[r * 128 + t + j * 64]) * PI_F;
            float s, c; sincosf(sp, &s, &c);
#pragma unroll
            for (int v = 0; v < 8; v++) { Sc[j][v] += c * g[v]; Ss[j][v] += s * g[v]; }
        }
    }
    size_t base = (size_t)blk * 2048;
#pragma unroll
    for (int j = 0; j < 2; j++)
#pragma unroll
        for (int v = 0; v < 8; v++) {
            csum[base + (t + j * 64) * 8 + v]        = Sc[j][v];
            csum[base + 1024 + (t + j * 64) * 8 + v] = Ss[j][v];
        }
}

// exclusive scan of chunk states over nc.  8192 lanes.
__global__ __launch_bounds__(256)
void kv_scan(float* __restrict__ csum)
{
    int t = blockIdx.x * 256 + threadIdx.x;   // (b, cs, pv)
    int pv = t & 1023; int cs = (t >> 10) & 1; int b = t >> 11;
    float run = 0.f;
    for (int nc = 0; nc < NC_; nc++) {
        size_t o = ((size_t)(b * NC_ + nc)) * 2048 + cs * 1024 + pv;
        float v = csum[o]; csum[o] = run; run += v;
    }
}

// KV retrieve: walk chunk inclusively, butterfly-reduce over P.
__global__ void kv_retrieve(const float* __restrict__ sppre, const float* __restrict__ kesgo,
                            const float* __restrict__ gv, const float* __restrict__ gni,
                            const float* __restrict__ csum, float* __restrict__ kvr)
{
    int blk = blockIdx.x; int nc = blk & (NC_ - 1), b = blk >> 7;
    int t = threadIdx.x;
    float Sc[2][8], Ss[2][8];
    size_t base = (size_t)blk * 2048;
#pragma unroll
    for (int j = 0; j < 2; j++)
#pragma unroll
        for (int v = 0; v < 8; v++) {
            Sc[j][v] = csum[base + (t + j * 64) * 8 + v];
            Ss[j][v] = csum[base + 1024 + (t + j * 64) * 8 + v];
        }
    for (int i = 0; i < CH_; i++) {
        size_t r = (size_t)(b * L_ + nc * CH_ + i);
        float g[8];
#pragma unroll
        for (int v = 0; v < 8; v++) g[v] = gv[r * 8 + v];
        float part[8];
#pragma unroll
        for (int v = 0; v < 8; v++) part[v] = 0.f;
#pragma unroll
        for (int j = 0; j < 2; j++) {
            float sp = tanhf(sppre[r * 128 + t + j * 64]) * PI_F;
            float s, c; sincosf(sp, &s, &c);
#pragma unroll
            for (int v = 0; v < 8; v++) { Sc[j][v] += c * g[v]; Ss[j][v] += s * g[v]; }
            float qp = tanhf(kesgo[r * 144 + t + j * 64]) * PI_F;
            float sq, cq; sincosf(qp, &sq, &cq);
#pragma unroll
            for (int v = 0; v < 8; v++) part[v] += cq * Sc[j][v] + sq * Ss[j][v];
        }
#pragma unroll
        for (int ofs = 1; ofs < 64; ofs <<= 1)
#pragma unroll
            for (int v = 0; v < 8; v++) part[v] += __shfl_xor(part[v], ofs, 64);
        if (t == 0) {
            float sc = gni[r] * 0.08838834764831845f;   // 1/sqrt(128)
#pragma unroll
            for (int v = 0; v < 8; v++) kvr[r * 8 + v] = part[v] * sc;
        }
    }
}

// kv_out linear (K=8) into combined cols [1024,1536), bf16
__global__ __launch_bounds__(256)
void kvo_lin(const float* __restrict__ kvr, const float* __restrict__ w,
             const float* __restrict__ bias, u16* __restrict__ combined)
{
    int idx = blockIdx.x * 256 + threadIdx.x;   // BL*512
    int n = idx & 511; size_t m = idx >> 9;
    float acc = bias[n];
#pragma unroll
    for (int k = 0; k < 8; k++) acc += kvr[m * 8 + k] * w[n * 8 + k];
    combined[m * 2560 + 1024 + n] = f2b(acc);
}

// layernorm over 2560, in place on bf16 combined
__global__ __launch_bounds__(256)
void ln_rows(u16* __restrict__ combined, const float* __restrict__ g, const float* __restrict__ bb)
{
    size_t m = blockIdx.x; int t = threadIdx.x;
    float v[10]; float s = 0.f, s2 = 0.f;
#pragma unroll
    for (int i = 0; i < 10; i++) {
        float x = b2f(combined[m * 2560 + t + i * 256]);
        v[i] = x; s += x; s2 += x * x;
    }
    __shared__ float sh[2][256];
    sh[0][t] = s; sh[1][t] = s2;
    __syncthreads();
    for (int ofs = 128; ofs > 0; ofs >>= 1) {
        if (t < ofs) { sh[0][t] += sh[0][t + ofs]; sh[1][t] += sh[1][t + ofs]; }
        __syncthreads();
    }
    float mean = sh[0][0] * (1.0f / 2560.0f);
    float var  = sh[1][0] * (1.0f / 2560.0f) - mean * mean;
    float rstd = rsqrtf(var + 1e-5f);
#pragma unroll
    for (int i = 0; i < 10; i++) {
        int c = t + i * 256;
        combined[m * 2560 + c] = f2b((v[i] - mean) * rstd * g[c] + bb[c]);
    }
}

// ---------------------------------------------------------------------------
extern "C" void kernel_launch(void* const* d_in, const int* in_sizes, int n_in,
                              void* d_out, int out_size, void* d_ws, size_t ws_size,
                              hipStream_t stream)
{
    const float* x     = (const float*)d_in[0];
    const float* lc_w  = (const float*)d_in[1];
    const float* lc_b  = (const float*)d_in[2];
    const float* cg_w  = (const float*)d_in[3];
    const float* cg_b  = (const float*)d_in[4];
    const float* cp_w  = (const float*)d_in[5];
    const float* cp_b  = (const float*)d_in[6];
    const float* tw_w  = (const float*)d_in[7];
    const float* tw_b  = (const float*)d_in[8];
    const float* omega_scale = (const float*)d_in[9];
    const float* pi0_w = (const float*)d_in[10];
    const float* pi0_b = (const float*)d_in[11];
    const float* pi2_w = (const float*)d_in[12];
    const float* pi2_b = (const float*)d_in[13];
    const float* m1v_w = (const float*)d_in[14];
    const float* m1v_b = (const float*)d_in[15];
    const float* m1o_w = (const float*)d_in[16];
    const float* m1o_b = (const float*)d_in[17];
    const float* mag_w = (const float*)d_in[18];
    const float* mag_b = (const float*)d_in[19];
    const float* mag_scale = (const float*)d_in[20];
    const float* qo_w  = (const float*)d_in[21];
    const float* qo_b  = (const float*)d_in[22];
    const float* ke_w  = (const float*)d_in[23];
    const float* ke_b  = (const float*)d_in[24];
    const float* ve_w  = (const float*)d_in[25];
    const float* ve_b  = (const float*)d_in[26];
    const float* sk0_w = (const float*)d_in[27];
    const float* sk0_b = (const float*)d_in[28];
    const float* sk2_w = (const float*)d_in[29];
    const float* sk2_b = (const float*)d_in[30];
    const float* sg_w  = (const float*)d_in[31];
    const float* sg_b  = (const float*)d_in[32];
    const float* kvo_w = (const float*)d_in[33];
    const float* kvo_b = (const float*)d_in[34];
    const float* ln_g  = (const float*)d_in[35];
    const float* ln_b  = (const float*)d_in[36];
    const float* o1_w  = (const float*)d_in[37];
    const float* o1_b  = (const float*)d_in[38];
    const float* o2_w  = (const float*)d_in[39];
    const float* o2_b  = (const float*)d_in[40];
    float* out = (float*)d_out;

    char* base = (char*)d_ws;
    size_t off = 0;
    auto alloc = [&](size_t bytes) -> void* {
        void* p = base + off;
        off += (bytes + 255) & ~(size_t)255;
        return p;
    };

    u16*   wcat1  = (u16*)  alloc((size_t)2560 * 512 * 2);
    float* bcat1  = (float*)alloc(2560 * 4);
    u16*   kesgw  = (u16*)  alloc((size_t)256 * 512 * 2);
    float* kesgb  = (float*)alloc(256 * 4);
    u16*   pi2w   = (u16*)  alloc((size_t)512 * 512 * 2);
    u16*   cpw    = (u16*)  alloc((size_t)512 * 512 * 2);
    u16*   sk0w   = (u16*)  alloc((size_t)512 * 1024 * 2);
    u16*   sk2w   = (u16*)  alloc((size_t)128 * 512 * 2);
    u16*   m1ow   = (u16*)  alloc((size_t)512 * 512 * 2);
    u16*   o1w    = (u16*)  alloc((size_t)1024 * 2560 * 2);
    u16*   o2w    = (u16*)  alloc((size_t)512 * 1024 * 2);
    u16*   xcat   = (u16*)  alloc((size_t)BL * 1024 * 2);
    u16*   out1   = (u16*)  alloc((size_t)BL * 2560 * 2);
    float* phib   = (float*)alloc((size_t)BL * 512 * 4);
    float* phi    = (float*)alloc((size_t)BL * 512 * 4);
    float* kesgo  = (float*)alloc((size_t)BL * 144 * 4);
    u16*   convg  = (u16*)  alloc((size_t)BL * 512 * 2);
    u16*   posret = (u16*)  alloc((size_t)BL * 512 * 2);
    u16*   sk0g   = (u16*)  alloc((size_t)BL * 512 * 2);
    float* sppre  = (float*)alloc((size_t)BL * 128 * 4);
    u16*   combined = (u16*)alloc((size_t)BL * 2560 * 2);
    u16*   o1g    = (u16*)  alloc((size_t)BL * 1024 * 2);
    float* cs_o   = (float*)alloc((size_t)4 * 16 * 512 * 4);
    float* cs_x   = (float*)alloc((size_t)4 * 16 * 512 * 4);
    float* cs_m   = (float*)alloc((size_t)4 * 16 * 512 * 4);
    float* cs_wc  = (float*)alloc((size_t)4 * 16 * 512 * 4);
    float* cs_ws  = (float*)alloc((size_t)4 * 16 * 512 * 4);
    float* gni    = (float*)alloc((size_t)BL * 4);
    float* gv     = (float*)alloc((size_t)BL * 8 * 4);
    float* kvcs   = (float*)alloc((size_t)4 * NC_ * 2048 * 4);
    float* kvr    = (float*)alloc((size_t)BL * 8 * 4);
    (void)ws_size; (void)in_sizes; (void)n_in; (void)out_size;

    // 1. weight prep
    prep_weights<<<23307, 256, 0, stream>>>(
        tw_w, pi0_w, m1v_w, mag_w, qo_w, ke_w, ve_w, sg_w,
        pi2_w, cp_w, sk0_w, sk2_w, m1o_w, o1_w, o2_w,
        tw_b, pi0_b, m1v_b, mag_b, qo_b, ke_b, ve_b, sg_b,
        wcat1, bcat1, kesgw, kesgb, pi2w, cpw, sk0w, sk2w, m1ow, o1w, o2w);
    // 2. conv branch input + cast x into xcat
    conv_gate<<<16384, 256, 0, stream>>>(x, lc_w, lc_b, cg_w, cg_b, convg, xcat);
    // 3. pass-1 fused GEMM: [omega | gelu(pi0) | v1 | mag | qoff]
    gemm_bt<EPI_PASS1><<<dim3(64, 20), 256, 0, stream>>>(xcat, 1024, wcat1, bcat1,
                                                         out1, 2560, 2560, 512, nullptr);
    // 4. pi2 -> phi_base (A = gelu'd pi0 slice of out1)
    gemm_bt<EPI_F32><<<dim3(64, 4), 256, 0, stream>>>(out1 + 512, 2560, pi2w, pi2_b,
                                                      phib, 512, 512, 512, nullptr);
    // 5. ke/ve/sg fused GEMM
    gemm_bt<EPI_F32><<<dim3(64, 2), 256, 0, stream>>>(xcat, 1024, kesgw, kesgb,
                                                      kesgo, 144, 144, 512, nullptr);
    // 6-10. chunked scans (phi, magnitude memory, context_avg)
    scan_a<<<512, 256, 0, stream>>>(out1, x, omega_scale, mag_scale, cs_o, cs_x, cs_m);
    scan_ex3<<<8, 256, 0, stream>>>(cs_o, cs_x, cs_m);
    scan_c<<<512, 256, 0, stream>>>(out1, phib, omega_scale, mag_scale, cs_o, phi, cs_wc, cs_ws);
    scan_ex2<<<8, 256, 0, stream>>>(cs_wc, cs_ws);
    scan_e<<<512, 256, 0, stream>>>(out1, phi, x, mag_scale, cs_m, cs_x, cs_wc, cs_ws,
                                    posret, xcat, combined);
    // 11. store-gate scan + gated values
    gate_scan<<<4, 256, 0, stream>>>(kesgo, gni, gv);
    // 12. sk0 (gelu) on [x | context_avg]
    gemm_bt<EPI_GELU_BF16><<<dim3(64, 4), 256, 0, stream>>>(xcat, 1024, sk0w, sk0_b,
                                                            sk0g, 512, 512, 1024, nullptr);
    // 13. sk2 -> storage phase pre-tanh
    gemm_bt<EPI_F32><<<dim3(64, 1), 256, 0, stream>>>(sk0g, 512, sk2w, sk2_b,
                                                      sppre, 128, 128, 512, nullptr);
    // 14-16. KV memory (chunk=16, 128 chunks/batch)
    kv_chunk<<<4 * NC_, 64, 0, stream>>>(sppre, gv, kvcs);
    kv_scan<<<32, 256, 0, stream>>>(kvcs);
    kv_retrieve<<<4 * NC_, 64, 0, stream>>>(sppre, kesgo, gv, gni, kvcs, kvr);
    // 17. kv_out linear
    kvo_lin<<<16384, 256, 0, stream>>>(kvr, kvo_w, kvo_b, combined);
    // 18. conv projection -> combined[:, 0:512)
    gemm_bt<EPI_BF16><<<dim3(64, 4), 256, 0, stream>>>(convg, 512, cpw, cp_b,
                                                       combined, 2560, 512, 512, nullptr);
    // 19. pos_out -> combined[:, 512:1024)
    gemm_bt<EPI_BF16><<<dim3(64, 4), 256, 0, stream>>>(posret, 512, m1ow, m1o_b,
                                                       combined + 512, 2560, 512, 512, nullptr);
    // 20. layernorm in place
    ln_rows<<<8192, 256, 0, stream>>>(combined, ln_g, ln_b);
    // 21. o1 + gelu
    gemm_bt<EPI_GELU_BF16><<<dim3(64, 8), 256, 0, stream>>>(combined, 2560, o1w, o1_b,
                                                            o1g, 1024, 1024, 2560, nullptr);
    // 22. o2 + residual -> out
    gemm_bt<EPI_RESID_F32><<<dim3(64, 4), 256, 0, stream>>>(o1g, 1024, o2w, o2_b,
                                                            out, 512, 512, 1024, x);
}

// Round 3
// 653.387 us; speedup vs baseline: 1.0641x; 1.0085x over previous
//
#include <hip/hip_runtime.h>
#include <cstdint>

typedef unsigned short u16;
typedef short short8 __attribute__((ext_vector_type(8)));
typedef float floatx4 __attribute__((ext_vector_type(4)));

#define B_ 4
#define L_ 2048
#define D_ 512
#define P_ 128
#define V_ 8
#define BL (B_ * L_)        // 8192
#define NC_ 128             // KV chunks per batch
#define CH_ 16              // KV chunk length
#define PI_F 3.14159265358979323846f

__device__ inline u16 f2b(float f) {
    unsigned u = __float_as_uint(f);
    unsigned r = u + 0x7FFFu + ((u >> 16) & 1u);
    return (u16)(r >> 16);
}
__device__ inline float b2f(u16 h) {
    return __uint_as_float(((unsigned)h) << 16);
}
__device__ inline float gelu_f(float v) {
    return 0.5f * v * (1.0f + erff(v * 0.70710678118654752f));
}
__device__ inline float sigm(float v) {
    return 1.0f / (1.0f + __expf(-v));
}
__device__ inline float tanh_fast(float v) {
    return 1.0f - 2.0f / (1.0f + __expf(2.0f * v));
}

// async global->LDS, 16B per lane. LDS dest is wave-uniform base + lane*16.
__device__ inline void async16(const u16* g, u16* l) {
    __builtin_amdgcn_global_load_lds(
        (const __attribute__((address_space(1))) unsigned int*)g,
        (__attribute__((address_space(3))) unsigned int*)l, 16, 0, 0);
}

extern __shared__ u16 smem_dyn[];   // 12288 B for all gemm64 wrappers

// ---------------------------------------------------------------------------
// 64x128-tile bf16 MFMA GEMM body (128 threads = 2 waves).
// C[m,n] = epi( sum_k A[m,k]*W[n,k] + bias[n] ).  W rows stride ldw.
// ---------------------------------------------------------------------------
enum { EPI_F32 = 0, EPI_BF16 = 1, EPI_GELU_BF16 = 2, EPI_RESID_F32 = 3,
       EPI_PASS1 = 4, EPI_ATOMIC = 5 };

__device__ __forceinline__ void gemm64_body(
    const u16* __restrict__ A, int lda,
    const u16* __restrict__ W, const float* __restrict__ bias,
    void* __restrict__ Cout, int ldc, int N, int K, int ldw,
    const float* __restrict__ resid, int mt, int nt, int epi)
{
    u16* As = smem_dyn;             // 64*32
    u16* Bs = smem_dyn + 64 * 32;   // 128*32
    const int tid  = threadIdx.x;
    const int lane = tid & 63;
    const int w    = tid >> 6;      // 0..1
    const int l16  = lane & 15, quad = lane >> 4;

    floatx4 acc[4][4] = {};

    const u16* Ab = A + (size_t)(mt * 64) * lda;
    const u16* Wb = W + (size_t)(nt * 128) * ldw;
    const int srow = lane >> 2;
    const int scol = (lane & 3) * 8;

    const u16* ga0 = Ab + (size_t)(w * 32 + srow) * lda + scol;
    const u16* ga1 = Ab + (size_t)(w * 32 + 16 + srow) * lda + scol;
    const u16* gb0 = Wb + (size_t)(w * 64 + srow) * ldw + scol;
    const u16* gb1 = Wb + (size_t)(w * 64 + 16 + srow) * ldw + scol;
    const u16* gb2 = Wb + (size_t)(w * 64 + 32 + srow) * ldw + scol;
    const u16* gb3 = Wb + (size_t)(w * 64 + 48 + srow) * ldw + scol;
    u16* la0 = &As[(w * 32) * 32];
    u16* la1 = &As[(w * 32 + 16) * 32];
    u16* lb0 = &Bs[(w * 64) * 32];
    u16* lb1 = &Bs[(w * 64 + 16) * 32];
    u16* lb2 = &Bs[(w * 64 + 32) * 32];
    u16* lb3 = &Bs[(w * 64 + 48) * 32];

    for (int k0 = 0; k0 < K; k0 += 32) {
        __syncthreads();
        async16(ga0 + k0, la0);
        async16(ga1 + k0, la1);
        async16(gb0 + k0, lb0);
        async16(gb1 + k0, lb1);
        async16(gb2 + k0, lb2);
        async16(gb3 + k0, lb3);
        __syncthreads();
        short8 a[4], b[4];
#pragma unroll
        for (int i = 0; i < 4; i++)
            a[i] = *(const short8*)(&As[(i * 16 + l16) * 32 + quad * 8]);
#pragma unroll
        for (int j = 0; j < 4; j++)
            b[j] = *(const short8*)(&Bs[(w * 64 + j * 16 + l16) * 32 + quad * 8]);
#pragma unroll
        for (int i = 0; i < 4; i++)
#pragma unroll
            for (int j = 0; j < 4; j++)
                acc[i][j] = __builtin_amdgcn_mfma_f32_16x16x32_bf16(a[i], b[j], acc[i][j], 0, 0, 0);
    }

#pragma unroll
    for (int i = 0; i < 4; i++) {
#pragma unroll
        for (int j = 0; j < 4; j++) {
#pragma unroll
            for (int r = 0; r < 4; r++) {
                int grow = mt * 64 + i * 16 + quad * 4 + r;
                int gcol = nt * 128 + w * 64 + j * 16 + l16;
                if (gcol < N) {
                    float bi = bias ? bias[gcol] : 0.0f;
                    float v = acc[i][j][r] + bi;
                    size_t off = (size_t)grow * ldc + gcol;
                    if (epi == EPI_F32)            ((float*)Cout)[off] = v;
                    else if (epi == EPI_BF16)      ((u16*)Cout)[off] = f2b(v);
                    else if (epi == EPI_GELU_BF16) ((u16*)Cout)[off] = f2b(gelu_f(v));
                    else if (epi == EPI_PASS1) {
                        float vv = (gcol >= 512 && gcol < 1024) ? gelu_f(v) : v;
                        ((u16*)Cout)[off] = f2b(vv);
                    }
                    else if (epi == EPI_RESID_F32) ((float*)Cout)[off] = v + resid[off];
                    else                           atomicAdd(&((float*)Cout)[off], v);
                }
            }
        }
    }
}

__global__ __launch_bounds__(128)
void gemm64(const u16* __restrict__ A, int lda,
            const u16* __restrict__ W, const float* __restrict__ bias,
            void* __restrict__ C, int ldc, int N, int K, int epi,
            const float* __restrict__ resid)
{
    gemm64_body(A, lda, W, bias, C, ldc, N, K, K, resid, blockIdx.x, blockIdx.y, epi);
}

// pass1 (N=2560,y 0..19) + ke/ve/sg (N=144,y 20..21) + conv proj (N=512,y 22..25)
__global__ __launch_bounds__(128)
void mega1(const u16* __restrict__ xcat, const u16* __restrict__ convg,
           const u16* __restrict__ wcat1, const float* __restrict__ bcat1,
           const u16* __restrict__ kesgw, const float* __restrict__ kesgb,
           const u16* __restrict__ cpw, const float* __restrict__ cp_b,
           u16* __restrict__ out1, float* __restrict__ kesgo, u16* __restrict__ combined)
{
    int y = blockIdx.y, mt = blockIdx.x;
    if (y < 20)
        gemm64_body(xcat, 1024, wcat1, bcat1, out1, 2560, 2560, 512, 512, nullptr, mt, y, EPI_PASS1);
    else if (y < 22)
        gemm64_body(xcat, 1024, kesgw, kesgb, kesgo, 144, 144, 512, 512, nullptr, mt, y - 20, EPI_F32);
    else
        gemm64_body(convg, 512, cpw, cp_b, combined, 2560, 512, 512, 512, nullptr, mt, y - 22, EPI_BF16);
}

// pos_out (y 0..3) + sk0 (y 4..7)
__global__ __launch_bounds__(128)
void mega2(const u16* __restrict__ posret, const u16* __restrict__ xcat,
           const u16* __restrict__ m1ow, const float* __restrict__ m1o_b,
           const u16* __restrict__ sk0w, const float* __restrict__ sk0_b,
           u16* __restrict__ combined, u16* __restrict__ sk0g)
{
    int y = blockIdx.y, mt = blockIdx.x;
    if (y < 4)
        gemm64_body(posret, 512, m1ow, m1o_b, combined + 512, 2560, 512, 512, 512, nullptr, mt, y, EPI_BF16);
    else
        gemm64_body(xcat, 1024, sk0w, sk0_b, sk0g, 512, 512, 1024, 1024, nullptr, mt, y - 4, EPI_GELU_BF16);
}

// split-K GEMM with f32 atomic accumulate (output must be pre-zeroed)
__global__ __launch_bounds__(128)
void gemm64_sk(const u16* __restrict__ A, int lda,
               const u16* __restrict__ W, int ldw, const float* __restrict__ bias,
               float* __restrict__ C, int ldc, int N, int Kchunk)
{
    int kz = blockIdx.z;
    gemm64_body(A + kz * Kchunk, lda, W + kz * Kchunk, kz == 0 ? bias : nullptr,
                C, ldc, N, Kchunk, ldw, nullptr, blockIdx.x, blockIdx.y, EPI_ATOMIC);
}

// ---------------------------------------------------------------------------
// Weight prep: cast fp32 weights -> bf16, build concatenations + pads.
// ---------------------------------------------------------------------------
__global__ __launch_bounds__(256)
void prep_weights(const float* tw, const float* pi0, const float* m1v, const float* mag, const float* qo,
                  const float* ke, const float* ve, const float* sg,
                  const float* pi2, const float* cp, const float* sk0, const float* sk2,
                  const float* m1o, const float* o1, const float* o2,
                  const float* tw_b, const float* pi0_b, const float* m1v_b, const float* mag_b, const float* qo_b,
                  const float* ke_b, const float* ve_b, const float* sg_b,
                  u16* wcat1, float* bcat1, u16* kesgw, float* kesgb,
                  u16* pi2w, u16* cpw, u16* sk0w, u16* sk2w, u16* m1ow, u16* o1w, u16* o2w)
{
    int idx = blockIdx.x * 256 + threadIdx.x;
    const int n0 = 2560 * 512;
    const int n1 = n0 + 256 * 512;
    const int n2 = n1 + 512 * 512;
    const int n3 = n2 + 512 * 512;
    const int n4 = n3 + 512 * 1024;
    const int n5 = n4 + 128 * 512;
    const int n6 = n5 + 512 * 512;
    const int n7 = n6 + 1024 * 2560;
    const int n8 = n7 + 512 * 1024;
    const int n9 = n8 + 2560;
    const int n10 = n9 + 256;
    if (idx < n0) {
        int r = idx >> 9, k = idx & 511;
        const float* s = (r < 512) ? tw : (r < 1024) ? pi0 : (r < 1536) ? m1v : (r < 2048) ? mag : qo;
        wcat1[idx] = f2b(s[(r & 511) * 512 + k]);
    } else if (idx < n1) {
        int i = idx - n0; int r = i >> 9, k = i & 511;
        float v;
        if (r < 128)      v = ke[r * 512 + k];
        else if (r < 136) v = ve[(r - 128) * 512 + k];
        else if (r == 136) v = sg[k];
        else               v = 0.0f;
        kesgw[i] = f2b(v);
    }
    else if (idx < n2) { int i = idx - n1; pi2w[i] = f2b(pi2[i]); }
    else if (idx < n3) { int i = idx - n2; cpw[i]  = f2b(cp[i]); }
    else if (idx < n4) { int i = idx - n3; sk0w[i] = f2b(sk0[i]); }
    else if (idx < n5) { int i = idx - n4; sk2w[i] = f2b(sk2[i]); }
    else if (idx < n6) { int i = idx - n5; m1ow[i] = f2b(m1o[i]); }
    else if (idx < n7) { int i = idx - n6; o1w[i]  = f2b(o1[i]); }
    else if (idx < n8) { int i = idx - n7; o2w[i]  = f2b(o2[i]); }
    else if (idx < n9) {
        int i = idx - n8;
        const float* s = (i < 512) ? tw_b : (i < 1024) ? pi0_b : (i < 1536) ? m1v_b : (i < 2048) ? mag_b : qo_b;
        bcat1[i] = s[i & 511];
    } else if (idx < n10) {
        int i = idx - n9;
        kesgb[i] = (i < 128) ? ke_b[i] : (i < 136) ? ve_b[i - 128] : (i == 136) ? sg_b[0] : 0.0f;
    }
}

// depthwise causal conv (K=4) gated branch + cast x into xcat cols [0,512)
__global__ __launch_bounds__(256)
void conv_gate(const float* __restrict__ x,
               const float* __restrict__ lcw, const float* __restrict__ lcb,
               const float* __restrict__ cgw, const float* __restrict__ cgb,
               u16* __restrict__ out, u16* __restrict__ xcat)
{
    int idx = blockIdx.x * 256 + threadIdx.x;   // over BL*512
    int d = idx & 511; int bl = idx >> 9;
    int l = bl & (L_ - 1); int b = bl >> 11;
    float a0 = 0.f, a1 = 0.f, xv3 = 0.f;
#pragma unroll
    for (int k = 0; k < 4; k++) {
        int ls = l - 3 + k;
        if (ls >= 0) {
            float xv = x[((size_t)(b * L_ + ls)) * 512 + d];
            if (k == 3) xv3 = xv;
            a0 += xv * lcw[d * 4 + k];
            a1 += xv * cgw[d * 4 + k];
        }
    }
    a0 += lcb[d];
    a1 = sigm(a1 + cgb[d]);
    out[idx] = f2b(a0 * a1);
    xcat[(size_t)bl * 1024 + d] = f2b(xv3);
}

// ---------------------------------------------------------------------------
// Chunked scans over L.  Grid: 512 blocks = b(4) x dt(8) x nc(16); block 256 =
// dl(64 lanes over d) x lg(4 groups of 32 l's).  Chunk = 128 l's.
// scan_a emits per-chunk sums; scan_c / scan_e self-compute chunk prefixes.
// ---------------------------------------------------------------------------
__global__ __launch_bounds__(256)
void scan_a(const u16* __restrict__ out1, const float* __restrict__ x,
            const float* __restrict__ oscale, const float* __restrict__ msc,
            float* __restrict__ cs_o, float* __restrict__ cs_x, float* __restrict__ cs_m)
{
    int blk = blockIdx.x;
    int nc = blk & 15, dt = (blk >> 4) & 7, b = blk >> 7;
    int t = threadIdx.x; int dl = t & 63, lg = t >> 6;
    int d = dt * 64 + dl;
    float os = fabsf(oscale[d]);
    float ms = fabsf(msc[0]);
    float so = 0.f, sx = 0.f, sm = 0.f;
    int l0 = nc * 128 + lg * 32;
    for (int i = 0; i < 32; i++) {
        size_t r = (size_t)(b * L_ + l0 + i);
        so += b2f(out1[r * 2560 + d]) * os;
        sm += sigm(b2f(out1[r * 2560 + 1536 + d])) * ms;
        sx += x[r * 512 + d];
    }
    __shared__ float sh[3][4][64];
    sh[0][lg][dl] = so; sh[1][lg][dl] = sx; sh[2][lg][dl] = sm;
    __syncthreads();
    if (t < 64) {
        float a = 0.f, xx = 0.f, m = 0.f;
        for (int g = 0; g < 4; g++) { a += sh[0][g][t]; xx += sh[1][g][t]; m += sh[2][g][t]; }
        size_t o = ((size_t)(b * 16 + nc)) * 512 + dt * 64 + t;
        cs_o[o] = a; cs_x[o] = xx; cs_m[o] = m;
    }
}

__global__ __launch_bounds__(256)
void scan_c(const u16* __restrict__ out1, const float* __restrict__ phib,
            const float* __restrict__ oscale, const float* __restrict__ msc,
            const float* __restrict__ cs_o,
            float* __restrict__ phi, float* __restrict__ cs_wc, float* __restrict__ cs_ws)
{
    int blk = blockIdx.x;
    int nc = blk & 15, dt = (blk >> 4) & 7, b = blk >> 7;
    int t = threadIdx.x; int dl = t & 63, lg = t >> 6;
    int d = dt * 64 + dl;
    float os = fabsf(oscale[d]);
    float ms = fabsf(msc[0]);
    int l0 = nc * 128 + lg * 32;
    float so = 0.f;
    for (int i = 0; i < 32; i++) {
        size_t r = (size_t)(b * L_ + l0 + i);
        so += b2f(out1[r * 2560 + d]) * os;
    }
    __shared__ float sh[4][64];
    __shared__ float shw[2][4][64];
    sh[lg][dl] = so;
    __syncthreads();
    float pre = 0.f;
    for (int p = 0; p < nc; p++) pre += cs_o[((size_t)(b * 16 + p)) * 512 + d];
    for (int g = 0; g < lg; g++) pre += sh[g][dl];
    float cum = pre, swc = 0.f, sws = 0.f;
    for (int i = 0; i < 32; i++) {
        size_t r = (size_t)(b * L_ + l0 + i);
        cum += b2f(out1[r * 2560 + d]) * os;
        float ph = phib[r * 512 + d] + cum;
        phi[r * 512 + d] = ph;
        float mg = sigm(b2f(out1[r * 2560 + 1536 + d])) * ms;
        float wv = mg * b2f(out1[r * 2560 + 1024 + d]);
        float s = __sinf(ph), c = __cosf(ph);
        swc += wv * c; sws += wv * s;
    }
    shw[0][lg][dl] = swc; shw[1][lg][dl] = sws;
    __syncthreads();
    if (t < 64) {
        float a = 0.f, bb = 0.f;
        for (int g = 0; g < 4; g++) { a += shw[0][g][t]; bb += shw[1][g][t]; }
        size_t o = ((size_t)(b * 16 + nc)) * 512 + dt * 64 + t;
        cs_wc[o] = a; cs_ws[o] = bb;
    }
}

__global__ __launch_bounds__(256)
void scan_e(const u16* __restrict__ out1, const float* __restrict__ phi,
            const float* __restrict__ x, const float* __restrict__ msc,
            const float* __restrict__ cs_m, const float* __restrict__ cs_x,
            const float* __restrict__ cs_wc, const float* __restrict__ cs_ws,
            u16* __restrict__ posret, u16* __restrict__ xcat, u16* __restrict__ combined)
{
    int blk = blockIdx.x;
    int nc = blk & 15, dt = (blk >> 4) & 7, b = blk >> 7;
    int t = threadIdx.x; int dl = t & 63, lg = t >> 6;
    int d = dt * 64 + dl;
    float ms = fabsf(msc[0]);
    int l0 = nc * 128 + lg * 32;
    float sm = 0.f, swc = 0.f, sws = 0.f, sx = 0.f;
    for (int i = 0; i < 32; i++) {
        size_t r = (size_t)(b * L_ + l0 + i);
        float ph = phi[r * 512 + d];
        float mg = sigm(b2f(out1[r * 2560 + 1536 + d])) * ms;
        float wv = mg * b2f(out1[r * 2560 + 1024 + d]);
        float s = __sinf(ph), c = __cosf(ph);
        sm += mg; swc += wv * c; sws += wv * s; sx += x[r * 512 + d];
    }
    __shared__ float sh[4][4][64];
    sh[0][lg][dl] = sm; sh[1][lg][dl] = swc; sh[2][lg][dl] = sws; sh[3][lg][dl] = sx;
    __syncthreads();
    float cm = 0.f, cwc = 0.f, cws = 0.f, cx = 0.f;
    for (int p = 0; p < nc; p++) {
        size_t o = ((size_t)(b * 16 + p)) * 512 + d;
        cm += cs_m[o]; cwc += cs_wc[o]; cws += cs_ws[o]; cx += cs_x[o];
    }
    for (int g = 0; g < lg; g++) {
        cm += sh[0][g][dl]; cwc += sh[1][g][dl]; cws += sh[2][g][dl]; cx += sh[3][g][dl];
    }
    const float invsqD = 0.044194173824159216f;  // 1/sqrt(512)
    for (int i = 0; i < 32; i++) {
        int l = l0 + i;
        size_t r = (size_t)(b * L_ + l);
        float ph = phi[r * 512 + d];
        float mg = sigm(b2f(out1[r * 2560 + 1536 + d])) * ms;
        float wv = mg * b2f(out1[r * 2560 + 1024 + d]);
        float xv = x[r * 512 + d];
        float s = __sinf(ph), c = __cosf(ph);
        cm += mg; cwc += wv * c; cws += wv * s; cx += xv;
        float smag = sqrtf(cm + 1e-8f);
        float m1c = cwc / smag, m1s = cws / smag;
        float phq = ph + b2f(out1[r * 2560 + 2048 + d]);
        float sq = __sinf(phq), cq = __cosf(phq);
        float pr = (m1c * cq + m1s * sq) * invsqD;
        posret[r * 512 + d] = f2b(pr);
        xcat[r * 1024 + 512 + d] = f2b(cx / (float)(l + 1));
        combined[r * 2560 + 1536 + d] = f2b(xv * c);
        combined[r * 2560 + 2048 + d] = f2b(xv * s);
    }
}

// store-gate scan (gni only).  Grid 4 (b), block 1024, 2 l's per thread.
__global__ __launch_bounds__(1024)
void gate_scan(const float* __restrict__ kesgo, float* __restrict__ gni)
{
    int b = blockIdx.x; int t = threadIdx.x;
    float s0 = sigm(kesgo[((size_t)(b * L_ + 2 * t)) * 144 + 136]);
    float s1 = sigm(kesgo[((size_t)(b * L_ + 2 * t + 1)) * 144 + 136]);
    float s = s0 + s1;
    __shared__ float sh[1024];
    sh[t] = s;
    __syncthreads();
    for (int ofs = 1; ofs < 1024; ofs <<= 1) {
        float v = (t >= ofs) ? sh[t - ofs] : 0.f;
        __syncthreads();
        sh[t] += v;
        __syncthreads();
    }
    float excl = sh[t] - s;
    float c0 = excl + s0, c1 = c0 + s1;
    gni[b * L_ + 2 * t]     = rsqrtf(fmaxf(c0, 1.0f));
    gni[b * L_ + 2 * t + 1] = rsqrtf(fmaxf(c1, 1.0f));
}

// KV chunk-state sums (gv computed inline).  Grid B*NC_, block 64: lane covers p=t,p+64.
__global__ __launch_bounds__(64)
void kv_chunk(const float* __restrict__ sppre, const float* __restrict__ kesgo,
              float* __restrict__ csum)
{
    int blk = blockIdx.x; int nc = blk & (NC_ - 1), b = blk >> 7;
    int t = threadIdx.x;
    float Sc[2][8] = {}, Ss[2][8] = {};
    for (int i = 0; i < CH_; i++) {
        size_t r = (size_t)(b * L_ + nc * CH_ + i);
        float sgate = sigm(kesgo[r * 144 + 136]);
        float g[8];
#pragma unroll
        for (int v = 0; v < 8; v++) g[v] = kesgo[r * 144 + 128 + v] * sgate;
#pragma unroll
        for (int j = 0; j < 2; j++) {
            float sp = tanh_fast(sppre[r * 128 + t + j * 64]) * PI_F;
            float s = __sinf(sp), c = __cosf(sp);
#pragma unroll
            for (int v = 0; v < 8; v++) { Sc[j][v] += c * g[v]; Ss[j][v] += s * g[v]; }
        }
    }
    size_t base = (size_t)blk * 2048;
#pragma unroll
    for (int j = 0; j < 2; j++)
#pragma unroll
        for (int v = 0; v < 8; v++) {
            csum[base + (t + j * 64) * 8 + v]        = Sc[j][v];
            csum[base + 1024 + (t + j * 64) * 8 + v] = Ss[j][v];
        }
}

// exclusive scan of chunk states over nc (separate in/out so loads pipeline)
__global__ __launch_bounds__(256)
void kv_scan(const float* __restrict__ cin, float* __restrict__ cex)
{
    int t = blockIdx.x * 256 + threadIdx.x;   // (b, cs, pv)
    int pv = t & 1023; int cs = (t >> 10) & 1; int b = t >> 11;
    float run = 0.f;
    for (int nc = 0; nc < NC_; nc++) {
        size_t o = ((size_t)(b * NC_ + nc)) * 2048 + cs * 1024 + pv;
        cex[o] = run; run += cin[o];
    }
}

// KV retrieve + fused kv_out linear -> combined cols [1024,1536)
__global__ __launch_bounds__(64)
void kv_retrieve(const float* __restrict__ sppre, const float* __restrict__ kesgo,
                 const float* __restrict__ gni, const float* __restrict__ cex,
                 const float* __restrict__ kvo_w, const float* __restrict__ kvo_b,
                 u16* __restrict__ combined)
{
    int blk = blockIdx.x; int nc = blk & (NC_ - 1), b = blk >> 7;
    int t = threadIdx.x;
    const int nb = t * 8;                 // this lane's 8 output cols
    float wr[8][8], br[8];
#pragma unroll
    for (int n = 0; n < 8; n++) {
        *(float4*)&wr[n][0] = *(const float4*)&kvo_w[(nb + n) * 8];
        *(float4*)&wr[n][4] = *(const float4*)&kvo_w[(nb + n) * 8 + 4];
        br[n] = kvo_b[nb + n];
    }
    float Sc[2][8], Ss[2][8];
    size_t base = (size_t)blk * 2048;
#pragma unroll
    for (int j = 0; j < 2; j++)
#pragma unroll
        for (int v = 0; v < 8; v++) {
            Sc[j][v] = cex[base + (t + j * 64) * 8 + v];
            Ss[j][v] = cex[base + 1024 + (t + j * 64) * 8 + v];
        }
    for (int i = 0; i < CH_; i++) {
        size_t r = (size_t)(b * L_ + nc * CH_ + i);
        float sgate = sigm(kesgo[r * 144 + 136]);
        float g[8];
#pragma unroll
        for (int v = 0; v < 8; v++) g[v] = kesgo[r * 144 + 128 + v] * sgate;
        float part[8];
#pragma unroll
        for (int v = 0; v < 8; v++) part[v] = 0.f;
#pragma unroll
        for (int j = 0; j < 2; j++) {
            float sp = tanh_fast(sppre[r * 128 + t + j * 64]) * PI_F;
            float s = __sinf(sp), c = __cosf(sp);
#pragma unroll
            for (int v = 0; v < 8; v++) { Sc[j][v] += c * g[v]; Ss[j][v] += s * g[v]; }
            float qp = tanh_fast(kesgo[r * 144 + t + j * 64]) * PI_F;
            float sq = __sinf(qp), cq = __cosf(qp);
#pragma unroll
            for (int v = 0; v < 8; v++) part[v] += cq * Sc[j][v] + sq * Ss[j][v];
        }
#pragma unroll
        for (int ofs = 1; ofs < 64; ofs <<= 1)
#pragma unroll
            for (int v = 0; v < 8; v++) part[v] += __shfl_xor(part[v], ofs, 64);
        float sc = gni[r] * 0.08838834764831845f;   // 1/sqrt(128)
        float pv[8];
#pragma unroll
        for (int v = 0; v < 8; v++) pv[v] = part[v] * sc;
        u16 outv[8];
#pragma unroll
        for (int n = 0; n < 8; n++) {
            float a = br[n];
#pragma unroll
            for (int v = 0; v < 8; v++) a += pv[v] * wr[n][v];
            outv[n] = f2b(a);
        }
        *(uint4*)&combined[r * 2560 + 1024 + nb] = *(const uint4*)outv;
    }
}

// layernorm over 2560, in place on bf16 combined.  Block 320 (5 waves), b128 I/O.
__global__ __launch_bounds__(320)
void ln_rows(u16* __restrict__ combined, const float* __restrict__ g, const float* __restrict__ bb)
{
    size_t m = blockIdx.x; int t = threadIdx.x;   // 0..319, one oct each
    u16 vv[8];
    *(uint4*)vv = *(const uint4*)&combined[m * 2560 + t * 8];
    float f[8]; float s = 0.f, s2 = 0.f;
#pragma unroll
    for (int k = 0; k < 8; k++) { f[k] = b2f(vv[k]); s += f[k]; s2 += f[k] * f[k]; }
#pragma unroll
    for (int ofs = 1; ofs < 64; ofs <<= 1) {
        s  += __shfl_xor(s, ofs, 64);
        s2 += __shfl_xor(s2, ofs, 64);
    }
    __shared__ float shs[5], shs2[5];
    int wv = t >> 6;
    if ((t & 63) == 0) { shs[wv] = s; shs2[wv] = s2; }
    __syncthreads();
    float S = 0.f, S2 = 0.f;
#pragma unroll
    for (int i = 0; i < 5; i++) { S += shs[i]; S2 += shs2[i]; }
    float mean = S * (1.0f / 2560.0f);
    float var  = S2 * (1.0f / 2560.0f) - mean * mean;
    float rstd = rsqrtf(var + 1e-5f);
#pragma unroll
    for (int k = 0; k < 8; k++) {
        int c = t * 8 + k;
        vv[k] = f2b((f[k] - mean) * rstd * g[c] + bb[c]);
    }
    *(uint4*)&combined[m * 2560 + t * 8] = *(const uint4*)vv;
}

// ---------------------------------------------------------------------------
extern "C" void kernel_launch(void* const* d_in, const int* in_sizes, int n_in,
                              void* d_out, int out_size, void* d_ws, size_t ws_size,
                              hipStream_t stream)
{
    const float* x     = (const float*)d_in[0];
    const float* lc_w  = (const float*)d_in[1];
    const float* lc_b  = (const float*)d_in[2];
    const float* cg_w  = (const float*)d_in[3];
    const float* cg_b  = (const float*)d_in[4];
    const float* cp_w  = (const float*)d_in[5];
    const float* cp_b  = (const float*)d_in[6];
    const float* tw_w  = (const float*)d_in[7];
    const float* tw_b  = (const float*)d_in[8];
    const float* omega_scale = (const float*)d_in[9];
    const float* pi0_w = (const float*)d_in[10];
    const float* pi0_b = (const float*)d_in[11];
    const float* pi2_w = (const float*)d_in[12];
    const float* pi2_b = (const float*)d_in[13];
    const float* m1v_w = (const float*)d_in[14];
    const float* m1v_b = (const float*)d_in[15];
    const float* m1o_w = (const float*)d_in[16];
    const float* m1o_b = (const float*)d_in[17];
    const float* mag_w = (const float*)d_in[18];
    const float* mag_b = (const float*)d_in[19];
    const float* mag_scale = (const float*)d_in[20];
    const float* qo_w  = (const float*)d_in[21];
    const float* qo_b  = (const float*)d_in[22];
    const float* ke_w  = (const float*)d_in[23];
    const float* ke_b  = (const float*)d_in[24];
    const float* ve_w  = (const float*)d_in[25];
    const float* ve_b  = (const float*)d_in[26];
    const float* sk0_w = (const float*)d_in[27];
    const float* sk0_b = (const float*)d_in[28];
    const float* sk2_w = (const float*)d_in[29];
    const float* sk2_b = (const float*)d_in[30];
    const float* sg_w  = (const float*)d_in[31];
    const float* sg_b  = (const float*)d_in[32];
    const float* kvo_w = (const float*)d_in[33];
    const float* kvo_b = (const float*)d_in[34];
    const float* ln_g  = (const float*)d_in[35];
    const float* ln_b  = (const float*)d_in[36];
    const float* o1_w  = (const float*)d_in[37];
    const float* o1_b  = (const float*)d_in[38];
    const float* o2_w  = (const float*)d_in[39];
    const float* o2_b  = (const float*)d_in[40];
    float* out = (float*)d_out;

    char* base = (char*)d_ws;
    size_t off = 0;
    auto alloc = [&](size_t bytes) -> void* {
        void* p = base + off;
        off += (bytes + 255) & ~(size_t)255;
        return p;
    };

    u16*   wcat1  = (u16*)  alloc((size_t)2560 * 512 * 2);
    float* bcat1  = (float*)alloc(2560 * 4);
    u16*   kesgw  = (u16*)  alloc((size_t)256 * 512 * 2);
    float* kesgb  = (float*)alloc(256 * 4);
    u16*   pi2w   = (u16*)  alloc((size_t)512 * 512 * 2);
    u16*   cpw    = (u16*)  alloc((size_t)512 * 512 * 2);
    u16*   sk0w   = (u16*)  alloc((size_t)512 * 1024 * 2);
    u16*   sk2w   = (u16*)  alloc((size_t)128 * 512 * 2);
    u16*   m1ow   = (u16*)  alloc((size_t)512 * 512 * 2);
    u16*   o1w    = (u16*)  alloc((size_t)1024 * 2560 * 2);
    u16*   o2w    = (u16*)  alloc((size_t)512 * 1024 * 2);
    u16*   xcat   = (u16*)  alloc((size_t)BL * 1024 * 2);
    u16*   out1   = (u16*)  alloc((size_t)BL * 2560 * 2);
    float* phib   = (float*)alloc((size_t)BL * 512 * 4);
    float* phi    = (float*)alloc((size_t)BL * 512 * 4);
    float* kesgo  = (float*)alloc((size_t)BL * 144 * 4);
    u16*   convg  = (u16*)  alloc((size_t)BL * 512 * 2);
    u16*   posret = (u16*)  alloc((size_t)BL * 512 * 2);
    u16*   sk0g   = (u16*)  alloc((size_t)BL * 512 * 2);
    float* sppre  = (float*)alloc((size_t)BL * 128 * 4);
    u16*   combined = (u16*)alloc((size_t)BL * 2560 * 2);
    u16*   o1g    = (u16*)  alloc((size_t)BL * 1024 * 2);
    float* cs_o   = (float*)alloc((size_t)4 * 16 * 512 * 4);
    float* cs_x   = (float*)alloc((size_t)4 * 16 * 512 * 4);
    float* cs_m   = (float*)alloc((size_t)4 * 16 * 512 * 4);
    float* cs_wc  = (float*)alloc((size_t)4 * 16 * 512 * 4);
    float* cs_ws  = (float*)alloc((size_t)4 * 16 * 512 * 4);
    float* gni    = (float*)alloc((size_t)BL * 4);
    float* kvcs   = (float*)alloc((size_t)4 * NC_ * 2048 * 4);
    float* kvex   = (float*)alloc((size_t)4 * NC_ * 2048 * 4);
    (void)ws_size; (void)in_sizes; (void)n_in; (void)out_size;

    const size_t SMEM = 12288;

    // 1. weight prep
    prep_weights<<<23307, 256, 0, stream>>>(
        tw_w, pi0_w, m1v_w, mag_w, qo_w, ke_w, ve_w, sg_w,
        pi2_w, cp_w, sk0_w, sk2_w, m1o_w, o1_w, o2_w,
        tw_b, pi0_b, m1v_b, mag_b, qo_b, ke_b, ve_b, sg_b,
        wcat1, bcat1, kesgw, kesgb, pi2w, cpw, sk0w, sk2w, m1ow, o1w, o2w);
    // 2. conv branch input + cast x into xcat
    conv_gate<<<16384, 256, 0, stream>>>(x, lc_w, lc_b, cg_w, cg_b, convg, xcat);
    // 3. mega1: pass1 [omega | gelu(pi0) | v1 | mag | qoff] + ke/ve/sg + conv proj
    mega1<<<dim3(128, 26), 128, SMEM, stream>>>(xcat, convg, wcat1, bcat1,
                                                kesgw, kesgb, cpw, cp_b,
                                                out1, kesgo, combined);
    // 4. pi2 -> phi_base (A = gelu'd pi0 slice of out1)
    gemm64<<<dim3(128, 4), 128, SMEM, stream>>>(out1 + 512, 2560, pi2w, pi2_b,
                                                phib, 512, 512, 512, EPI_F32, nullptr);
    // 5-7. chunked scans (phi, magnitude memory, context_avg)
    scan_a<<<512, 256, 0, stream>>>(out1, x, omega_scale, mag_scale, cs_o, cs_x, cs_m);
    scan_c<<<512, 256, 0, stream>>>(out1, phib, omega_scale, mag_scale, cs_o, phi, cs_wc, cs_ws);
    scan_e<<<512, 256, 0, stream>>>(out1, phi, x, mag_scale, cs_m, cs_x, cs_wc, cs_ws,
                                    posret, xcat, combined);
    // 8. store-gate scan
    gate_scan<<<4, 1024, 0, stream>>>(kesgo, gni);
    // 9. mega2: pos_out + sk0(gelu)
    mega2<<<dim3(128, 8), 128, SMEM, stream>>>(posret, xcat, m1ow, m1o_b,
                                               sk0w, sk0_b, combined, sk0g);
    // 10. sk2 -> storage phase pre-tanh (split-K=4 atomic)
    hipMemsetAsync(sppre, 0, (size_t)BL * 128 * 4, stream);
    gemm64_sk<<<dim3(128, 1, 4), 128, SMEM, stream>>>(sk0g, 512, sk2w, 512, sk2_b,
                                                      sppre, 128, 128, 128);
    // 11-13. KV memory (chunk=16, 128 chunks/batch)
    kv_chunk<<<4 * NC_, 64, 0, stream>>>(sppre, kesgo, kvcs);
    kv_scan<<<32, 256, 0, stream>>>(kvcs, kvex);
    kv_retrieve<<<4 * NC_, 64, 0, stream>>>(sppre, kesgo, gni, kvex, kvo_w, kvo_b, combined);
    // 14. layernorm in place
    ln_rows<<<8192, 320, 0, stream>>>(combined, ln_g, ln_b);
    // 15. o1 + gelu
    gemm64<<<dim3(128, 8), 128, SMEM, stream>>>(combined, 2560, o1w, o1_b,
                                                o1g, 1024, 1024, 2560, EPI_GELU_BF16, nullptr);
    // 16. o2 + residual -> out
    gemm64<<<dim3(128, 4), 128, SMEM, stream>>>(o1g, 1024, o2w, o2_b,
                                                out, 512, 512, 1024, EPI_RESID_F32, x);
}